// Round 5
// baseline (544.637 us; speedup 1.0000x reference)
//
#include <hip/hip_runtime.h>

#define N_NODES 50000
#define N_EDGES 800000
#define N_GRAPHS 64
#define NEG_SLOPE 0.2f
// 1/sqrt(1 + 1e-5), BN eval-mode scale
#define BN_RSQ 0.9999950000374997f
#define NB_SCAN ((N_NODES + 255) / 256)  // 196 blocks in the node-space scan

typedef __bf16 bf16x8 __attribute__((ext_vector_type(8)));
typedef float floatx4 __attribute__((ext_vector_type(4)));

__device__ __forceinline__ float lrelu(float v) { return v > 0.0f ? v : NEG_SLOPE * v; }

// bf16 <-> f32 (round-to-nearest-even)
__device__ __forceinline__ float b2f(unsigned short u) {
    return __uint_as_float(((unsigned int)u) << 16);
}
__device__ __forceinline__ unsigned short f2b(float f) {
    unsigned int u = __float_as_uint(f);
    return (unsigned short)((u + 0x7fffu + ((u >> 16) & 1u)) >> 16);
}
// unpack 2 bf16 from one dword (1 instr each: shl / and)
__device__ __forceinline__ float blo(unsigned int d) { return __uint_as_float(d << 16); }
__device__ __forceinline__ float bhi(unsigned int d) { return __uint_as_float(d & 0xffff0000u); }

// ---------------- fused prep: degree count + weight bf16 transpose (all layers) ----------------
// Wt[n*K+k] = bf16(W[k*N+n]) — MFMA B-fragment layout (also A-fragment of W^T).
__global__ void k_prep(const int* __restrict__ ei, int* __restrict__ deg,
                       const float* __restrict__ W1, const float* __restrict__ W2,
                       const float* __restrict__ W3, const float* __restrict__ W4,
                       unsigned short* __restrict__ Wt1, unsigned short* __restrict__ Wt2,
                       unsigned short* __restrict__ Wt3, unsigned short* __restrict__ Wt4) {
    int i = blockIdx.x * 256 + threadIdx.x;
    if (i < 32768) {  // W1: 128x256
        int k = i >> 8, n = i & 255;
        Wt1[n * 128 + k] = f2b(W1[i]);
    } else if (i < 49152) {  // W2: 256x64
        int j = i - 32768;
        int k = j >> 6, n = j & 63;
        Wt2[n * 256 + k] = f2b(W2[j]);
    } else if (i < 53248) {  // W3: 64x64
        int j = i - 49152;
        int k = j >> 6, n = j & 63;
        Wt3[n * 64 + k] = f2b(W3[j]);
    } else if (i < 57344) {  // W4: 64x64
        int j = i - 53248;
        int k = j >> 6, n = j & 63;
        Wt4[n * 64 + k] = f2b(W4[j]);
    }
    if (i < N_EDGES) atomicAdd(&deg[ei[N_EDGES + i]], 1);
}

// offsets via wave shuffle-scan + one atomic per wave; per-block degree histogram
// (LPT: bucket = 63 - min(deg,63) -> descending-degree sort); graph bounds.
__global__ __launch_bounds__(256) void k_offs(const int* __restrict__ deg, int* __restrict__ offs,
                                              int* __restrict__ total, const int* __restrict__ batch,
                                              int* __restrict__ bounds, int* __restrict__ bh) {
    __shared__ int lh[64];
    if (threadIdx.x < 64) lh[threadIdx.x] = 0;
    __syncthreads();
    if (blockIdx.x == 0 && threadIdx.x <= N_GRAPHS) {
        int g = threadIdx.x;
        int lo = 0, hi = N_NODES;
        while (lo < hi) {
            int mid = (lo + hi) >> 1;
            if (batch[mid] < g) lo = mid + 1; else hi = mid;
        }
        bounds[g] = lo;
    }
    int i = blockIdx.x * blockDim.x + threadIdx.x;
    int lane = threadIdx.x & 63;
    int v = (i < N_NODES) ? deg[i] : 0;
    int incl = v;
    for (int o = 1; o < 64; o <<= 1) {
        int t = __shfl_up(incl, o);
        if (lane >= o) incl += t;
    }
    int wtot = __shfl(incl, 63);
    int base = 0;
    if (lane == 0) base = atomicAdd(total, wtot);
    base = __shfl(base, 0);
    if (i < N_NODES) {
        offs[i] = base + incl - v;
        atomicAdd(&lh[63 - min(v, 63)], 1);  // LDS atomic, block-local; LPT flip
    }
    __syncthreads();
    if (threadIdx.x < 64) bh[blockIdx.x * 64 + threadIdx.x] = lh[threadIdx.x];
}

// single block: bucket totals -> exclusive bucket scan -> per-block bucket bases
__global__ __launch_bounds__(256) void k_pscan(const int* __restrict__ bh, int* __restrict__ bb) {
    __shared__ int partial[4][64];
    __shared__ int bbase[64];
    const int tid = threadIdx.x;
    const int b = tid & 63, q = tid >> 6;
    const int per = (NB_SCAN + 3) / 4;
    const int k0 = q * per, k1 = min(k0 + per, NB_SCAN);
    int s = 0;
    for (int k = k0; k < k1; ++k) s += bh[k * 64 + b];
    partial[q][b] = s;
    __syncthreads();
    if (tid < 64) {
        int tot = partial[0][tid] + partial[1][tid] + partial[2][tid] + partial[3][tid];
        int incl = tot;
        for (int o = 1; o < 64; o <<= 1) {
            int t2 = __shfl_up(incl, o);
            if (tid >= o) incl += t2;
        }
        bbase[tid] = incl - tot;
    }
    __syncthreads();
    int run = bbase[b];
    for (int q2 = 0; q2 < q; ++q2) run += partial[q2][b];
    for (int k = k0; k < k1; ++k) {
        bb[k * 64 + b] = run;
        run += bh[k * 64 + b];
    }
}

// merged: CSR fill (edge-space) + degree-sort scatter (first NB_SCAN blocks)
__global__ __launch_bounds__(256) void k_fillperm(const int* __restrict__ ei,
                                                  const int* __restrict__ offs,
                                                  int* __restrict__ cur, int* __restrict__ csr_src,
                                                  const int* __restrict__ deg,
                                                  const int* __restrict__ bb,
                                                  int* __restrict__ perm) {
    __shared__ int lcnt[64];
    if (blockIdx.x < NB_SCAN) {  // block-uniform branch: barrier is safe
        if (threadIdx.x < 64) lcnt[threadIdx.x] = 0;
        __syncthreads();
        int i = blockIdx.x * 256 + threadIdx.x;
        if (i < N_NODES) {
            int b = 63 - min(deg[i], 63);  // LPT flip
            int r = atomicAdd(&lcnt[b], 1);
            perm[bb[blockIdx.x * 64 + b] + r] = i;
        }
    }
    int e = blockIdx.x * 256 + threadIdx.x;
    if (e < N_EDGES) {
        int d = ei[N_EDGES + e];
        int pos = offs[d] + atomicAdd(&cur[d], 1);
        csr_src[pos] = ei[e];
    }
}

// ---------------- MFMA GEMM + fused attention dots (layer 1 only) ----------------
// C/D layout (m89-verified): row=quad*4+rg, col=ct*16+l16.
template <int K, int N, int HEADS, bool AF32>
__global__ __launch_bounds__(256) void k_mgemm(const void* __restrict__ Ap,
                                               const unsigned short* __restrict__ Bt,
                                               const float* __restrict__ asrc,
                                               const float* __restrict__ adst,
                                               unsigned short* __restrict__ out,
                                               float* __restrict__ es,
                                               float* __restrict__ ed, int rows) {
    constexpr int LDP = K + 8;
    __shared__ unsigned short As[64 * LDP];
    const int tid = threadIdx.x;
    const int r0 = blockIdx.x * 64;
    if (AF32) {
        const float* A = (const float*)Ap;
        for (int i = tid; i < 16 * K; i += 256) {
            int r = i / (K / 4), c4 = i % (K / 4);
            int row = r0 + r;
            float4 v = (row < rows) ? *(const float4*)&A[(size_t)row * K + c4 * 4]
                                    : make_float4(0.f, 0.f, 0.f, 0.f);
            ushort4 u;
            u.x = f2b(v.x); u.y = f2b(v.y); u.z = f2b(v.z); u.w = f2b(v.w);
            *(ushort4*)&As[r * LDP + c4 * 4] = u;
        }
    } else {
        const unsigned short* A = (const unsigned short*)Ap;
        for (int i = tid; i < 8 * K; i += 256) {
            int r = i / (K / 8), c8 = i % (K / 8);
            int row = r0 + r;
            uint4 v;
            if (row < rows) v = *(const uint4*)&A[(size_t)row * K + c8 * 8];
            else { v.x = v.y = v.z = v.w = 0; }
            *(uint4*)&As[r * LDP + c8 * 8] = v;
        }
    }
    __syncthreads();
    const int w = tid >> 6, lane = tid & 63;
    const int quad = lane >> 4, l16 = lane & 15;
    const int gr0 = r0 + w * 16 + quad * 4;
    bf16x8 afrag[K / 32];
#pragma unroll
    for (int kk = 0; kk < K / 32; ++kk)
        afrag[kk] = *(const bf16x8*)&As[(w * 16 + l16) * LDP + kk * 32 + quad * 8];
    float sacc[4] = {0.f, 0.f, 0.f, 0.f};
    float dacc[4] = {0.f, 0.f, 0.f, 0.f};
#pragma unroll 1
    for (int ct = 0; ct < N / 16; ++ct) {
        floatx4 acc = {0.f, 0.f, 0.f, 0.f};
#pragma unroll
        for (int kk = 0; kk < K / 32; ++kk) {
            const bf16x8 bfrag =
                *(const bf16x8*)&Bt[(size_t)(ct * 16 + l16) * K + kk * 32 + quad * 8];
            acc = __builtin_amdgcn_mfma_f32_16x16x32_bf16(afrag[kk], bfrag, acc, 0, 0, 0);
        }
        const int gc = ct * 16 + l16;
        const int hh = gc >> 6;
        const int f = gc & 63;
        const float as = asrc[hh * 64 + f];
        const float ad = adst[hh * 64 + f];
#pragma unroll
        for (int rg = 0; rg < 4; ++rg) {
            sacc[rg] = fmaf(acc[rg], as, sacc[rg]);
            dacc[rg] = fmaf(acc[rg], ad, dacc[rg]);
        }
#pragma unroll
        for (int rg = 0; rg < 4; ++rg) {
            int gr = gr0 + rg;
            if (gr < rows) out[(size_t)gr * N + gc] = f2b(acc[rg]);
        }
        if ((ct & 3) == 3) {
#pragma unroll
            for (int rg = 0; rg < 4; ++rg) {
                float s = sacc[rg], d = dacc[rg];
                for (int o = 1; o < 16; o <<= 1) {
                    s += __shfl_xor(s, o);
                    d += __shfl_xor(d, o);
                }
                if (l16 == 0) {
                    int gr = gr0 + rg;
                    if (gr < rows) {
                        es[(size_t)gr * HEADS + hh] = s;
                        ed[(size_t)gr * HEADS + hh] = d;
                    }
                }
                sacc[rg] = 0.f;
                dacc[rg] = 0.f;
            }
        }
    }
}

// ---------------- GAT layer 1 FUSED with layer-2 projection GEMM (NO barriers) ----------------
// Phase 1 (proven round-0 structure): 16-lane group per dst node, 4 nodes/wave,
// 16 nodes/block (grid 3125 exact). x1 row (bf16) lands in per-WAVE LDS.
// Phase 2 per wave, transposed: D = Wt2(64x256, A-operand, L1-resident) x x1^T
// (256 x 4 nodes as B-columns; lanes l16>=4 clamp to l16&3 -> D cols 4..15 are
// duplicates, discarded). MFMA D col l16 depends only on B col l16, so no
// zero-fill / no cross-wave data / no __syncthreads -> waves retire independently
// and memory stays saturated (round-4 barrier cost ~10us). Dots reduce over quad.
__global__ __launch_bounds__(256) void k_gat1f(
    const unsigned short* __restrict__ xW, const float* __restrict__ es, const float* __restrict__ ed,
    const int* __restrict__ offs, const int* __restrict__ deg, const int* __restrict__ csr,
    const int* __restrict__ perm, const float* __restrict__ bias,
    const unsigned short* __restrict__ Bt2, const float* __restrict__ as2,
    const float* __restrict__ ad2, unsigned short* __restrict__ outW,
    float* __restrict__ es2o, float* __restrict__ ed2o) {
    __shared__ float ps[4][4 * 68];          // [wave][grp*68 + j*4 + h]
    __shared__ int sbuf[4][64];              // [wave][grp*16 + j]
    __shared__ unsigned short As2[4][4 * 264];  // per-wave x1 rows, stride 264 (528B, 16B-mult)
    const int wv = threadIdx.x >> 6;
    const int lane = threadIdx.x & 63;
    const int grp = lane >> 4, t = lane & 15;
    const int h = t >> 2;
    const int pidx = blockIdx.x * 16 + wv * 4 + grp;  // 3125*16 = 50000 exact
    const int n = perm[pidx];
    const int off = offs[n];
    const int dg = deg[n];
    const float4 edv = *(const float4*)&ed[n * 4];
    const int cb = t * 16;

    float acc[16];
#pragma unroll
    for (int k = 0; k < 16; ++k) acc[k] = 0.f;
    float dsum = 0.f;

    for (int base = 0; base < dg; base += 16) {
        const int idx = base + t;
        int s_l = 0;
        float p0 = 0.f, p1 = 0.f, p2 = 0.f, p3 = 0.f;
        if (idx < dg) {
            s_l = csr[off + idx];
            const float4 ev = *(const float4*)&es[s_l * 4];
            p0 = __expf(lrelu(ev.x + edv.x));
            p1 = __expf(lrelu(ev.y + edv.y));
            p2 = __expf(lrelu(ev.z + edv.z));
            p3 = __expf(lrelu(ev.w + edv.w));
        }
        *(float4*)&ps[wv][grp * 68 + t * 4] = make_float4(p0, p1, p2, p3);
        sbuf[wv][grp * 16 + t] = s_l;
        const int cnt = min(16, dg - base);
        const int cntR = (cnt + 3) & ~3;
        for (int j = 0; j < cntR; j += 4) {
            const float pa = ps[wv][grp * 68 + (j + 0) * 4 + h];
            const float pb = ps[wv][grp * 68 + (j + 1) * 4 + h];
            const float pc = ps[wv][grp * 68 + (j + 2) * 4 + h];
            const float pd = ps[wv][grp * 68 + (j + 3) * 4 + h];
            const int sa = sbuf[wv][grp * 16 + j + 0];
            const int sb = sbuf[wv][grp * 16 + j + 1];
            const int sc = sbuf[wv][grp * 16 + j + 2];
            const int sd = sbuf[wv][grp * 16 + j + 3];
            const uint4 a0 = *(const uint4*)&xW[(size_t)sa * 256 + cb];
            const uint4 a1 = *(const uint4*)&xW[(size_t)sa * 256 + cb + 8];
            const uint4 b0 = *(const uint4*)&xW[(size_t)sb * 256 + cb];
            const uint4 b1 = *(const uint4*)&xW[(size_t)sb * 256 + cb + 8];
            const uint4 c0 = *(const uint4*)&xW[(size_t)sc * 256 + cb];
            const uint4 c1 = *(const uint4*)&xW[(size_t)sc * 256 + cb + 8];
            const uint4 d0 = *(const uint4*)&xW[(size_t)sd * 256 + cb];
            const uint4 d1 = *(const uint4*)&xW[(size_t)sd * 256 + cb + 8];
            dsum += (pa + pb) + (pc + pd);
            acc[0]  = fmaf(pa, blo(a0.x), acc[0]);
            acc[1]  = fmaf(pa, bhi(a0.x), acc[1]);
            acc[2]  = fmaf(pa, blo(a0.y), acc[2]);
            acc[3]  = fmaf(pa, bhi(a0.y), acc[3]);
            acc[4]  = fmaf(pa, blo(a0.z), acc[4]);
            acc[5]  = fmaf(pa, bhi(a0.z), acc[5]);
            acc[6]  = fmaf(pa, blo(a0.w), acc[6]);
            acc[7]  = fmaf(pa, bhi(a0.w), acc[7]);
            acc[8]  = fmaf(pa, blo(a1.x), acc[8]);
            acc[9]  = fmaf(pa, bhi(a1.x), acc[9]);
            acc[10] = fmaf(pa, blo(a1.y), acc[10]);
            acc[11] = fmaf(pa, bhi(a1.y), acc[11]);
            acc[12] = fmaf(pa, blo(a1.z), acc[12]);
            acc[13] = fmaf(pa, bhi(a1.z), acc[13]);
            acc[14] = fmaf(pa, blo(a1.w), acc[14]);
            acc[15] = fmaf(pa, bhi(a1.w), acc[15]);
            acc[0]  = fmaf(pb, blo(b0.x), acc[0]);
            acc[1]  = fmaf(pb, bhi(b0.x), acc[1]);
            acc[2]  = fmaf(pb, blo(b0.y), acc[2]);
            acc[3]  = fmaf(pb, bhi(b0.y), acc[3]);
            acc[4]  = fmaf(pb, blo(b0.z), acc[4]);
            acc[5]  = fmaf(pb, bhi(b0.z), acc[5]);
            acc[6]  = fmaf(pb, blo(b0.w), acc[6]);
            acc[7]  = fmaf(pb, bhi(b0.w), acc[7]);
            acc[8]  = fmaf(pb, blo(b1.x), acc[8]);
            acc[9]  = fmaf(pb, bhi(b1.x), acc[9]);
            acc[10] = fmaf(pb, blo(b1.y), acc[10]);
            acc[11] = fmaf(pb, bhi(b1.y), acc[11]);
            acc[12] = fmaf(pb, blo(b1.z), acc[12]);
            acc[13] = fmaf(pb, bhi(b1.z), acc[13]);
            acc[14] = fmaf(pb, blo(b1.w), acc[14]);
            acc[15] = fmaf(pb, bhi(b1.w), acc[15]);
            acc[0]  = fmaf(pc, blo(c0.x), acc[0]);
            acc[1]  = fmaf(pc, bhi(c0.x), acc[1]);
            acc[2]  = fmaf(pc, blo(c0.y), acc[2]);
            acc[3]  = fmaf(pc, bhi(c0.y), acc[3]);
            acc[4]  = fmaf(pc, blo(c0.z), acc[4]);
            acc[5]  = fmaf(pc, bhi(c0.z), acc[5]);
            acc[6]  = fmaf(pc, blo(c0.w), acc[6]);
            acc[7]  = fmaf(pc, bhi(c0.w), acc[7]);
            acc[8]  = fmaf(pc, blo(c1.x), acc[8]);
            acc[9]  = fmaf(pc, bhi(c1.x), acc[9]);
            acc[10] = fmaf(pc, blo(c1.y), acc[10]);
            acc[11] = fmaf(pc, bhi(c1.y), acc[11]);
            acc[12] = fmaf(pc, blo(c1.z), acc[12]);
            acc[13] = fmaf(pc, bhi(c1.z), acc[13]);
            acc[14] = fmaf(pc, blo(c1.w), acc[14]);
            acc[15] = fmaf(pc, bhi(c1.w), acc[15]);
            acc[0]  = fmaf(pd, blo(d0.x), acc[0]);
            acc[1]  = fmaf(pd, bhi(d0.x), acc[1]);
            acc[2]  = fmaf(pd, blo(d0.y), acc[2]);
            acc[3]  = fmaf(pd, bhi(d0.y), acc[3]);
            acc[4]  = fmaf(pd, blo(d0.z), acc[4]);
            acc[5]  = fmaf(pd, bhi(d0.z), acc[5]);
            acc[6]  = fmaf(pd, blo(d0.w), acc[6]);
            acc[7]  = fmaf(pd, bhi(d0.w), acc[7]);
            acc[8]  = fmaf(pd, blo(d1.x), acc[8]);
            acc[9]  = fmaf(pd, bhi(d1.x), acc[9]);
            acc[10] = fmaf(pd, blo(d1.y), acc[10]);
            acc[11] = fmaf(pd, bhi(d1.y), acc[11]);
            acc[12] = fmaf(pd, blo(d1.z), acc[12]);
            acc[13] = fmaf(pd, bhi(d1.z), acc[13]);
            acc[14] = fmaf(pd, blo(d1.w), acc[14]);
            acc[15] = fmaf(pd, bhi(d1.w), acc[15]);
        }
    }
    // x1 row -> per-wave LDS (bf16, same rounding as the old x1b path)
    const float inv = 1.0f / fmaxf(dsum, 1e-16f);
#pragma unroll
    for (int k4 = 0; k4 < 16; k4 += 4) {
        const int c = cb + k4;
        const float4 bv = *(const float4*)&bias[c];
        ushort4 o4;
        o4.x = f2b(fmaxf(fmaf(acc[k4 + 0], inv, bv.x), 0.f));
        o4.y = f2b(fmaxf(fmaf(acc[k4 + 1], inv, bv.y), 0.f));
        o4.z = f2b(fmaxf(fmaf(acc[k4 + 2], inv, bv.z), 0.f));
        o4.w = f2b(fmaxf(fmaf(acc[k4 + 3], inv, bv.w), 0.f));
        *(ushort4*)&As2[wv][grp * 264 + c] = o4;
    }
    // Phase 2: per-wave transposed mini-GEMM. D[f=ft*16+grp*4+rg][node=t<4].
    // A-frag = Wt2 rows (global, 32KB L1-resident); B-frag = own wave's x1 rows.
    const int nl = __shfl(n, (t & 3) * 16);  // node id for column t (valid t<4)
    float sred = 0.f, dred = 0.f;
#pragma unroll
    for (int ft = 0; ft < 4; ++ft) {
        floatx4 c2 = {0.f, 0.f, 0.f, 0.f};
#pragma unroll
        for (int kk = 0; kk < 8; ++kk) {
            const bf16x8 aw = *(const bf16x8*)&Bt2[(size_t)(ft * 16 + t) * 256 + kk * 32 + grp * 8];
            const bf16x8 bx = *(const bf16x8*)&As2[wv][(t & 3) * 264 + kk * 32 + grp * 8];
            c2 = __builtin_amdgcn_mfma_f32_16x16x32_bf16(aw, bx, c2, 0, 0, 0);
        }
        const float4 av = *(const float4*)&as2[ft * 16 + grp * 4];
        const float4 dv = *(const float4*)&ad2[ft * 16 + grp * 4];
        sred += c2[0] * av.x + c2[1] * av.y + c2[2] * av.z + c2[3] * av.w;
        dred += c2[0] * dv.x + c2[1] * dv.y + c2[2] * dv.z + c2[3] * dv.w;
        if (t < 4) {
            ushort4 o;
            o.x = f2b(c2[0]); o.y = f2b(c2[1]); o.z = f2b(c2[2]); o.w = f2b(c2[3]);
            *(ushort4*)&outW[(size_t)nl * 64 + ft * 16 + grp * 4] = o;
        }
    }
    sred += __shfl_xor(sred, 16); sred += __shfl_xor(sred, 32);
    dred += __shfl_xor(dred, 16); dred += __shfl_xor(dred, 32);
    if (grp == 0 && t < 4) {
        es2o[nl] = sred;
        ed2o[nl] = dred;
    }
}

// ---------------- GAT layers 2-3 FUSED with next-layer 64x64 GEMM (NO barriers) ----------------
// Phase 1: proven gatL body (8-lane group/node, 32 nodes/block). h row -> global fp32
// (residual/pool) + bf16 row -> per-WAVE LDS. Phase 2 per wave, transposed:
// D = Wtn(64x64, A, L1-resident) x h^T (8 node-columns; l16>=8 clamp, discarded).
template <bool RES>
__global__ __launch_bounds__(256) void k_gatLG(
    const unsigned short* __restrict__ xW, const float* __restrict__ es, const float* __restrict__ ed,
    const int* __restrict__ offs, const int* __restrict__ deg, const int* __restrict__ csr,
    const int* __restrict__ perm, const float* __restrict__ bias, const float* __restrict__ gam,
    const float* __restrict__ bet, float* __restrict__ hglob,
    const unsigned short* __restrict__ Btn, const float* __restrict__ asn,
    const float* __restrict__ adn, unsigned short* __restrict__ outW,
    float* __restrict__ esn, float* __restrict__ edn_o) {
    __shared__ float ps[4][64];
    __shared__ int sbuf[4][64];
    __shared__ unsigned short As2[4][8 * 72];  // per-wave h bf16 rows, stride 72 (144B, 16B-mult)
    const int wv = threadIdx.x >> 6;
    const int lane = threadIdx.x & 63;
    const int g8 = lane >> 3, t8 = lane & 7;
    const int pbase = blockIdx.x * 32;
    if (pbase + wv * 8 >= N_NODES) return;  // whole wave idle; kernel has no barriers
    const int pidx = pbase + wv * 8 + g8;
    const bool valid = pidx < N_NODES;
    const int n = perm[valid ? pidx : 0];
    const int off = offs[n];
    const int dg = valid ? deg[n] : 0;
    const float edn = valid ? ed[n] : 0.f;
    const int cb = t8 * 8;

    float acc[8];
#pragma unroll
    for (int k = 0; k < 8; ++k) acc[k] = 0.f;
    float dsum = 0.f;

    for (int base = 0; base < dg; base += 8) {
        const int idx = base + t8;
        int s_l = 0;
        float p_l = 0.f;
        if (idx < dg) {
            s_l = csr[off + idx];
            p_l = __expf(lrelu(es[s_l] + edn));
        }
        ps[wv][g8 * 8 + t8] = p_l;
        sbuf[wv][g8 * 8 + t8] = s_l;
        float pp[8];
        int ss[8];
#pragma unroll
        for (int q = 0; q < 8; ++q) {
            pp[q] = ps[wv][g8 * 8 + q];
            ss[q] = sbuf[wv][g8 * 8 + q];
        }
        uint4 u[8];
#pragma unroll
        for (int q = 0; q < 8; ++q) u[q] = *(const uint4*)&xW[(size_t)ss[q] * 64 + cb];
#pragma unroll
        for (int q = 0; q < 8; ++q) {
            dsum += pp[q];
            acc[0] = fmaf(pp[q], blo(u[q].x), acc[0]);
            acc[1] = fmaf(pp[q], bhi(u[q].x), acc[1]);
            acc[2] = fmaf(pp[q], blo(u[q].y), acc[2]);
            acc[3] = fmaf(pp[q], bhi(u[q].y), acc[3]);
            acc[4] = fmaf(pp[q], blo(u[q].z), acc[4]);
            acc[5] = fmaf(pp[q], bhi(u[q].z), acc[5]);
            acc[6] = fmaf(pp[q], blo(u[q].w), acc[6]);
            acc[7] = fmaf(pp[q], bhi(u[q].w), acc[7]);
        }
    }
    const float inv = 1.0f / fmaxf(dsum, 1e-16f);
    float hn[8];
#pragma unroll
    for (int k = 0; k < 8; ++k) {
        const int c = cb + k;
        const float y = fmaf(acc[k], inv, bias[c]);
        const float z = fmaxf(fmaf(gam[c] * y, BN_RSQ, bet[c]), 0.f);
        hn[k] = (RES && valid) ? hglob[(size_t)n * 64 + c] + z : z;
    }
    if (valid) {
        *(float4*)&hglob[(size_t)n * 64 + cb] = make_float4(hn[0], hn[1], hn[2], hn[3]);
        *(float4*)&hglob[(size_t)n * 64 + cb + 4] = make_float4(hn[4], hn[5], hn[6], hn[7]);
    }
    ushort4 u0, u1;
    u0.x = f2b(hn[0]); u0.y = f2b(hn[1]); u0.z = f2b(hn[2]); u0.w = f2b(hn[3]);
    u1.x = f2b(hn[4]); u1.y = f2b(hn[5]); u1.z = f2b(hn[6]); u1.w = f2b(hn[7]);
    *(ushort4*)&As2[wv][g8 * 72 + cb] = u0;
    *(ushort4*)&As2[wv][g8 * 72 + cb + 4] = u1;
    // Phase 2: per-wave transposed mini-GEMM. D[f=ft*16+quad*4+rg][node=l16<8].
    const int quad = lane >> 4, l16 = lane & 15;
    const int ncol = __shfl(n, (l16 & 7) * 8);
    const bool vcol = (pbase + wv * 8 + (l16 & 7)) < N_NODES;
    float sred = 0.f, dred = 0.f;
#pragma unroll
    for (int ft = 0; ft < 4; ++ft) {
        floatx4 c2 = {0.f, 0.f, 0.f, 0.f};
#pragma unroll
        for (int kk = 0; kk < 2; ++kk) {
            const bf16x8 aw = *(const bf16x8*)&Btn[(size_t)(ft * 16 + l16) * 64 + kk * 32 + quad * 8];
            const bf16x8 bx = *(const bf16x8*)&As2[wv][(l16 & 7) * 72 + kk * 32 + quad * 8];
            c2 = __builtin_amdgcn_mfma_f32_16x16x32_bf16(aw, bx, c2, 0, 0, 0);
        }
        const float4 av = *(const float4*)&asn[ft * 16 + quad * 4];
        const float4 dv = *(const float4*)&adn[ft * 16 + quad * 4];
        sred += c2[0] * av.x + c2[1] * av.y + c2[2] * av.z + c2[3] * av.w;
        dred += c2[0] * dv.x + c2[1] * dv.y + c2[2] * dv.z + c2[3] * dv.w;
        if (l16 < 8 && vcol) {
            ushort4 o;
            o.x = f2b(c2[0]); o.y = f2b(c2[1]); o.z = f2b(c2[2]); o.w = f2b(c2[3]);
            *(ushort4*)&outW[(size_t)ncol * 64 + ft * 16 + quad * 4] = o;
        }
    }
    sred += __shfl_xor(sred, 16); sred += __shfl_xor(sred, 32);
    dred += __shfl_xor(dred, 16); dred += __shfl_xor(dred, 32);
    if (quad == 0 && l16 < 8 && vcol) {
        esn[ncol] = sred;
        edn_o[ncol] = dred;
    }
}

// ---------------- final GAT layer (residual, no next GEMM, no bf16 out) ----------------
__global__ __launch_bounds__(256) void k_gatF(
    const unsigned short* __restrict__ xW, const float* __restrict__ es, const float* __restrict__ ed,
    const int* __restrict__ offs, const int* __restrict__ deg, const int* __restrict__ csr,
    const int* __restrict__ perm, const float* __restrict__ bias, const float* __restrict__ gam,
    const float* __restrict__ bet, float* __restrict__ h) {
    __shared__ float ps[4][64];
    __shared__ int sbuf[4][64];
    const int wv = threadIdx.x >> 6;
    const int lane = threadIdx.x & 63;
    const int grp = lane >> 3, t = lane & 7;
    const int pidx = blockIdx.x * 32 + wv * 8 + grp;
    if (pidx >= N_NODES) return;
    const int n = perm[pidx];
    const int off = offs[n];
    const int dg = deg[n];
    const float edn = ed[n];
    const int cb = t * 8;

    float acc[8];
#pragma unroll
    for (int k = 0; k < 8; ++k) acc[k] = 0.f;
    float dsum = 0.f;

    for (int base = 0; base < dg; base += 8) {
        const int idx = base + t;
        int s_l = 0;
        float p_l = 0.f;
        if (idx < dg) {
            s_l = csr[off + idx];
            p_l = __expf(lrelu(es[s_l] + edn));
        }
        ps[wv][grp * 8 + t] = p_l;
        sbuf[wv][grp * 8 + t] = s_l;
        float pp[8];
        int ss[8];
#pragma unroll
        for (int q = 0; q < 8; ++q) {
            pp[q] = ps[wv][grp * 8 + q];
            ss[q] = sbuf[wv][grp * 8 + q];
        }
        uint4 u[8];
#pragma unroll
        for (int q = 0; q < 8; ++q) u[q] = *(const uint4*)&xW[(size_t)ss[q] * 64 + cb];
#pragma unroll
        for (int q = 0; q < 8; ++q) {
            dsum += pp[q];
            acc[0] = fmaf(pp[q], blo(u[q].x), acc[0]);
            acc[1] = fmaf(pp[q], bhi(u[q].x), acc[1]);
            acc[2] = fmaf(pp[q], blo(u[q].y), acc[2]);
            acc[3] = fmaf(pp[q], bhi(u[q].y), acc[3]);
            acc[4] = fmaf(pp[q], blo(u[q].z), acc[4]);
            acc[5] = fmaf(pp[q], bhi(u[q].z), acc[5]);
            acc[6] = fmaf(pp[q], blo(u[q].w), acc[6]);
            acc[7] = fmaf(pp[q], bhi(u[q].w), acc[7]);
        }
    }
    const float inv = 1.0f / fmaxf(dsum, 1e-16f);
    float hn[8];
#pragma unroll
    for (int k = 0; k < 8; ++k) {
        const int c = cb + k;
        const float y = fmaf(acc[k], inv, bias[c]);
        const float z = fmaxf(fmaf(gam[c] * y, BN_RSQ, bet[c]), 0.f);
        hn[k] = h[(size_t)n * 64 + c] + z;
    }
    *(float4*)&h[(size_t)n * 64 + cb] = make_float4(hn[0], hn[1], hn[2], hn[3]);
    *(float4*)&h[(size_t)n * 64 + cb + 4] = make_float4(hn[4], hn[5], hn[6], hn[7]);
}

// ---------------- mean pool: one block per graph ----------------
__global__ __launch_bounds__(256) void k_pool2(const float* __restrict__ h,
                                               const int* __restrict__ bounds,
                                               float* __restrict__ hp) {
    __shared__ float part[4][64];
    const int g = blockIdx.x;
    const int lane = threadIdx.x & 63;
    const int wid = threadIdx.x >> 6;
    const int s = bounds[g], e = bounds[g + 1];
    float acc = 0.f;
    for (int n = s + wid; n < e; n += 4) acc += h[n * 64 + lane];
    part[wid][lane] = acc;
    __syncthreads();
    if (wid == 0) {
        float v = part[0][lane] + part[1][lane] + part[2][lane] + part[3][lane];
        hp[g * 64 + lane] = v / fmaxf((float)(e - s), 1.0f);
    }
}

// ---------------- MLP head, single block ----------------
__global__ __launch_bounds__(256) void k_head(const float* __restrict__ hpg,
                                              const float* __restrict__ Wh1,
                                              const float* __restrict__ bh1,
                                              const float* __restrict__ Wh2,
                                              const float* __restrict__ bh2,
                                              float* __restrict__ out) {
    __shared__ float hp[64 * 64];
    __shared__ float t1[64 * 128];
    const int tid = threadIdx.x;
    for (int i = tid; i < 64 * 64; i += 256) hp[i] = hpg[i];
    __syncthreads();
    for (int i = tid; i < 64 * 128; i += 256) {
        int g = i >> 7, j = i & 127;
        float s = bh1[j];
        for (int k = 0; k < 64; ++k) s = fmaf(hp[g * 64 + k], Wh1[k * 128 + j], s);
        t1[i] = fmaxf(s, 0.f);
    }
    __syncthreads();
    for (int i = tid; i < 640; i += 256) {
        int g = i / 10, j = i - g * 10;
        float s = bh2[j];
        for (int k = 0; k < 128; ++k) s = fmaf(t1[g * 128 + k], Wh2[k * 10 + j], s);
        out[i] = s;
    }
}

extern "C" void kernel_launch(void* const* d_in, const int* in_sizes, int n_in,
                              void* d_out, int out_size, void* d_ws, size_t ws_size,
                              hipStream_t stream) {
    const float* x = (const float*)d_in[1];
    const int* ei = (const int*)d_in[2];
    const int* batch = (const int*)d_in[3];
    const float* W1 = (const float*)d_in[4];
    const float* a_src1 = (const float*)d_in[5];
    const float* a_dst1 = (const float*)d_in[6];
    const float* b1 = (const float*)d_in[7];
    const float* W2 = (const float*)d_in[8];
    const float* a_src2 = (const float*)d_in[9];
    const float* a_dst2 = (const float*)d_in[10];
    const float* b2 = (const float*)d_in[11];
    const float* g2 = (const float*)d_in[12];
    const float* be2 = (const float*)d_in[13];
    const float* W3 = (const float*)d_in[14];
    const float* a_src3 = (const float*)d_in[15];
    const float* a_dst3 = (const float*)d_in[16];
    const float* b3 = (const float*)d_in[17];
    const float* g3 = (const float*)d_in[18];
    const float* be3 = (const float*)d_in[19];
    const float* W4 = (const float*)d_in[20];
    const float* a_src4 = (const float*)d_in[21];
    const float* a_dst4 = (const float*)d_in[22];
    const float* b4 = (const float*)d_in[23];
    const float* g4 = (const float*)d_in[24];
    const float* be4 = (const float*)d_in[25];
    const float* Wh1 = (const float*)d_in[26];
    const float* bh1 = (const float*)d_in[27];
    const float* Wh2 = (const float*)d_in[28];
    const float* bh2 = (const float*)d_in[29];
    float* out = (float*)d_out;

    // workspace layout
    char* p = (char*)d_ws;
    auto alloc = [&](size_t bytes) {
        void* r = (void*)p;
        p += (bytes + 255) & ~(size_t)255;
        return r;
    };
    unsigned short* bufA1 = (unsigned short*)alloc((size_t)N_NODES * 256 * 2);  // xW1 bf16
    unsigned short* bufB = (unsigned short*)alloc((size_t)N_NODES * 64 * 2);    // xW2 bf16
    unsigned short* bufC = (unsigned short*)alloc((size_t)N_NODES * 64 * 2);    // xW3 bf16
    unsigned short* bufD = (unsigned short*)alloc((size_t)N_NODES * 64 * 2);    // xW4 bf16
    float* h = (float*)alloc((size_t)N_NODES * 64 * 4);                         // h fp32
    float* es1 = (float*)alloc((size_t)N_NODES * 4 * 4);
    float* ed1 = (float*)alloc((size_t)N_NODES * 4 * 4);
    float* es2 = (float*)alloc((size_t)N_NODES * 4);
    float* ed2 = (float*)alloc((size_t)N_NODES * 4);
    float* es3 = (float*)alloc((size_t)N_NODES * 4);
    float* ed3 = (float*)alloc((size_t)N_NODES * 4);
    float* es4 = (float*)alloc((size_t)N_NODES * 4);
    float* ed4 = (float*)alloc((size_t)N_NODES * 4);
    int* offs = (int*)alloc((size_t)N_NODES * 4);
    int* csr = (int*)alloc((size_t)N_EDGES * 4);
    int* perm = (int*)alloc((size_t)N_NODES * 4);
    int* bounds = (int*)alloc((size_t)(N_GRAPHS + 1) * 4);
    int* bh_hist = (int*)alloc((size_t)NB_SCAN * 64 * 4);
    int* bb = (int*)alloc((size_t)NB_SCAN * 64 * 4);
    float* hpool = (float*)alloc((size_t)N_GRAPHS * 64 * 4);
    unsigned short* Wt1 = (unsigned short*)alloc((size_t)128 * 256 * 2);
    unsigned short* Wt2 = (unsigned short*)alloc((size_t)256 * 64 * 2);
    unsigned short* Wt3 = (unsigned short*)alloc((size_t)64 * 64 * 2);
    unsigned short* Wt4 = (unsigned short*)alloc((size_t)64 * 64 * 2);
    char* z0 = p;  // everything below gets zeroed each call
    int* deg = (int*)alloc((size_t)N_NODES * 4);
    int* cur = (int*)alloc((size_t)N_NODES * 4);
    int* total = (int*)alloc(256);
    size_t zbytes = (size_t)(p - z0);
    hipMemsetAsync(z0, 0, zbytes, stream);

    const int edgeBlocks = (N_EDGES + 255) / 256;
    const int mgemmBlocks = (N_NODES + 63) / 64;
    const int gat1Blocks = (N_NODES + 15) / 16;  // 3125 exact
    const int gatLBlocks = (N_NODES + 31) / 32;

    // fused prep: degree count + weight bf16 transposes
    k_prep<<<edgeBlocks, 256, 0, stream>>>(ei, deg, W1, W2, W3, W4, Wt1, Wt2, Wt3, Wt4);

    // CSR offsets + LPT histogram + graph bounds; bucket scan; merged fill+perm
    k_offs<<<NB_SCAN, 256, 0, stream>>>(deg, offs, total, batch, bounds, bh_hist);
    k_pscan<<<1, 256, 0, stream>>>(bh_hist, bb);
    k_fillperm<<<edgeBlocks, 256, 0, stream>>>(ei, offs, cur, csr, deg, bb, perm);

    // layer 1 GEMM: xW1 + attention dots
    k_mgemm<128, 256, 4, true><<<mgemmBlocks, 256, 0, stream>>>(x, Wt1, a_src1, a_dst1,
                                                                bufA1, es1, ed1, N_NODES);
    // layer 1 gather + FUSED layer-2 projection GEMM (x1 never hits HBM, barrier-free)
    k_gat1f<<<gat1Blocks, 256, 0, stream>>>(bufA1, es1, ed1, offs, deg, csr, perm, b1,
                                            Wt2, a_src2, a_dst2, bufB, es2, ed2);

    // layer 2 gather + BN + relu + FUSED layer-3 GEMM (barrier-free)
    k_gatLG<false><<<gatLBlocks, 256, 0, stream>>>(bufB, es2, ed2, offs, deg, csr, perm,
                                                   b2, g2, be2, h, Wt3, a_src3, a_dst3,
                                                   bufC, es3, ed3);
    // layer 3 residual gather + FUSED layer-4 GEMM (barrier-free)
    k_gatLG<true><<<gatLBlocks, 256, 0, stream>>>(bufC, es3, ed3, offs, deg, csr, perm,
                                                  b3, g3, be3, h, Wt4, a_src4, a_dst4,
                                                  bufD, es4, ed4);
    // layer 4 residual gather (final)
    k_gatF<<<gatLBlocks, 256, 0, stream>>>(bufD, es4, ed4, offs, deg, csr, perm, b4, g4, be4, h);

    // pool + head (batch sorted -> contiguous ranges, no atomics)
    k_pool2<<<N_GRAPHS, 256, 0, stream>>>(h, bounds, hpool);
    k_head<<<1, 256, 0, stream>>>(hpool, Wh1, bh1, Wh2, bh2, out);
}

// Round 7
// 507.136 us; speedup vs baseline: 1.0739x; 1.0739x over previous
//
#include <hip/hip_runtime.h>

#define N_NODES 50000
#define N_EDGES 800000
#define N_GRAPHS 64
#define NEG_SLOPE 0.2f
// 1/sqrt(1 + 1e-5), BN eval-mode scale
#define BN_RSQ 0.9999950000374997f
#define NB_SCAN ((N_NODES + 255) / 256)  // 196 blocks in the node-space scan

typedef __bf16 bf16x8 __attribute__((ext_vector_type(8)));
typedef float floatx4 __attribute__((ext_vector_type(4)));

__device__ __forceinline__ float lrelu(float v) { return v > 0.0f ? v : NEG_SLOPE * v; }

// bf16 <-> f32 (round-to-nearest-even)
__device__ __forceinline__ float b2f(unsigned short u) {
    return __uint_as_float(((unsigned int)u) << 16);
}
__device__ __forceinline__ unsigned short f2b(float f) {
    unsigned int u = __float_as_uint(f);
    return (unsigned short)((u + 0x7fffu + ((u >> 16) & 1u)) >> 16);
}
// unpack 2 bf16 from one dword (1 instr each: shl / and)
__device__ __forceinline__ float blo(unsigned int d) { return __uint_as_float(d << 16); }
__device__ __forceinline__ float bhi(unsigned int d) { return __uint_as_float(d & 0xffff0000u); }

// ---------------- fused prep: degree count + weight bf16 transpose (all layers) ----------------
// Wt[n*K+k] = bf16(W[k*N+n]) — MFMA B-fragment layout.
__global__ void k_prep(const int* __restrict__ ei, int* __restrict__ deg,
                       const float* __restrict__ W1, const float* __restrict__ W2,
                       const float* __restrict__ W3, const float* __restrict__ W4,
                       unsigned short* __restrict__ Wt1, unsigned short* __restrict__ Wt2,
                       unsigned short* __restrict__ Wt3, unsigned short* __restrict__ Wt4) {
    int i = blockIdx.x * 256 + threadIdx.x;
    if (i < 32768) {  // W1: 128x256
        int k = i >> 8, n = i & 255;
        Wt1[n * 128 + k] = f2b(W1[i]);
    } else if (i < 49152) {  // W2: 256x64
        int j = i - 32768;
        int k = j >> 6, n = j & 63;
        Wt2[n * 256 + k] = f2b(W2[j]);
    } else if (i < 53248) {  // W3: 64x64
        int j = i - 49152;
        int k = j >> 6, n = j & 63;
        Wt3[n * 64 + k] = f2b(W3[j]);
    } else if (i < 57344) {  // W4: 64x64
        int j = i - 53248;
        int k = j >> 6, n = j & 63;
        Wt4[n * 64 + k] = f2b(W4[j]);
    }
    if (i < N_EDGES) atomicAdd(&deg[ei[N_EDGES + i]], 1);
}

// offsets via wave shuffle-scan + one atomic per wave; per-block degree histogram
// (LPT: bucket = 63 - min(deg,63) -> descending-degree sort); graph bounds.
__global__ __launch_bounds__(256) void k_offs(const int* __restrict__ deg, int* __restrict__ offs,
                                              int* __restrict__ total, const int* __restrict__ batch,
                                              int* __restrict__ bounds, int* __restrict__ bh) {
    __shared__ int lh[64];
    if (threadIdx.x < 64) lh[threadIdx.x] = 0;
    __syncthreads();
    if (blockIdx.x == 0 && threadIdx.x <= N_GRAPHS) {
        int g = threadIdx.x;
        int lo = 0, hi = N_NODES;
        while (lo < hi) {
            int mid = (lo + hi) >> 1;
            if (batch[mid] < g) lo = mid + 1; else hi = mid;
        }
        bounds[g] = lo;
    }
    int i = blockIdx.x * blockDim.x + threadIdx.x;
    int lane = threadIdx.x & 63;
    int v = (i < N_NODES) ? deg[i] : 0;
    int incl = v;
    for (int o = 1; o < 64; o <<= 1) {
        int t = __shfl_up(incl, o);
        if (lane >= o) incl += t;
    }
    int wtot = __shfl(incl, 63);
    int base = 0;
    if (lane == 0) base = atomicAdd(total, wtot);
    base = __shfl(base, 0);
    if (i < N_NODES) {
        offs[i] = base + incl - v;
        atomicAdd(&lh[63 - min(v, 63)], 1);  // LDS atomic, block-local; LPT flip
    }
    __syncthreads();
    if (threadIdx.x < 64) bh[blockIdx.x * 64 + threadIdx.x] = lh[threadIdx.x];
}

// single block: bucket totals -> exclusive bucket scan -> per-block bucket bases
__global__ __launch_bounds__(256) void k_pscan(const int* __restrict__ bh, int* __restrict__ bb) {
    __shared__ int partial[4][64];
    __shared__ int bbase[64];
    const int tid = threadIdx.x;
    const int b = tid & 63, q = tid >> 6;
    const int per = (NB_SCAN + 3) / 4;
    const int k0 = q * per, k1 = min(k0 + per, NB_SCAN);
    int s = 0;
    for (int k = k0; k < k1; ++k) s += bh[k * 64 + b];
    partial[q][b] = s;
    __syncthreads();
    if (tid < 64) {
        int tot = partial[0][tid] + partial[1][tid] + partial[2][tid] + partial[3][tid];
        int incl = tot;
        for (int o = 1; o < 64; o <<= 1) {
            int t2 = __shfl_up(incl, o);
            if (tid >= o) incl += t2;
        }
        bbase[tid] = incl - tot;
    }
    __syncthreads();
    int run = bbase[b];
    for (int q2 = 0; q2 < q; ++q2) run += partial[q2][b];
    for (int k = k0; k < k1; ++k) {
        bb[k * 64 + b] = run;
        run += bh[k * 64 + b];
    }
}

// merged: CSR fill (edge-space) + degree-sort scatter (first NB_SCAN blocks)
__global__ __launch_bounds__(256) void k_fillperm(const int* __restrict__ ei,
                                                  const int* __restrict__ offs,
                                                  int* __restrict__ cur, int* __restrict__ csr_src,
                                                  const int* __restrict__ deg,
                                                  const int* __restrict__ bb,
                                                  int* __restrict__ perm) {
    __shared__ int lcnt[64];
    if (blockIdx.x < NB_SCAN) {  // block-uniform branch: barrier is safe
        if (threadIdx.x < 64) lcnt[threadIdx.x] = 0;
        __syncthreads();
        int i = blockIdx.x * 256 + threadIdx.x;
        if (i < N_NODES) {
            int b = 63 - min(deg[i], 63);  // LPT flip
            int r = atomicAdd(&lcnt[b], 1);
            perm[bb[blockIdx.x * 64 + b] + r] = i;
        }
    }
    int e = blockIdx.x * 256 + threadIdx.x;
    if (e < N_EDGES) {
        int d = ei[N_EDGES + e];
        int pos = offs[d] + atomicAdd(&cur[d], 1);
        csr_src[pos] = ei[e];
    }
}

// ---------------- MFMA GEMM + fused attention dots (layer 1 only) ----------------
// C/D layout (m89-verified): row=quad*4+rg, col=ct*16+l16.
template <int K, int N, int HEADS, bool AF32>
__global__ __launch_bounds__(256) void k_mgemm(const void* __restrict__ Ap,
                                               const unsigned short* __restrict__ Bt,
                                               const float* __restrict__ asrc,
                                               const float* __restrict__ adst,
                                               unsigned short* __restrict__ out,
                                               float* __restrict__ es,
                                               float* __restrict__ ed, int rows) {
    constexpr int LDP = K + 8;
    __shared__ unsigned short As[64 * LDP];
    const int tid = threadIdx.x;
    const int r0 = blockIdx.x * 64;
    if (AF32) {
        const float* A = (const float*)Ap;
        for (int i = tid; i < 16 * K; i += 256) {
            int r = i / (K / 4), c4 = i % (K / 4);
            int row = r0 + r;
            float4 v = (row < rows) ? *(const float4*)&A[(size_t)row * K + c4 * 4]
                                    : make_float4(0.f, 0.f, 0.f, 0.f);
            ushort4 u;
            u.x = f2b(v.x); u.y = f2b(v.y); u.z = f2b(v.z); u.w = f2b(v.w);
            *(ushort4*)&As[r * LDP + c4 * 4] = u;
        }
    } else {
        const unsigned short* A = (const unsigned short*)Ap;
        for (int i = tid; i < 8 * K; i += 256) {
            int r = i / (K / 8), c8 = i % (K / 8);
            int row = r0 + r;
            uint4 v;
            if (row < rows) v = *(const uint4*)&A[(size_t)row * K + c8 * 8];
            else { v.x = v.y = v.z = v.w = 0; }
            *(uint4*)&As[r * LDP + c8 * 8] = v;
        }
    }
    __syncthreads();
    const int w = tid >> 6, lane = tid & 63;
    const int quad = lane >> 4, l16 = lane & 15;
    const int gr0 = r0 + w * 16 + quad * 4;
    bf16x8 afrag[K / 32];
#pragma unroll
    for (int kk = 0; kk < K / 32; ++kk)
        afrag[kk] = *(const bf16x8*)&As[(w * 16 + l16) * LDP + kk * 32 + quad * 8];
    float sacc[4] = {0.f, 0.f, 0.f, 0.f};
    float dacc[4] = {0.f, 0.f, 0.f, 0.f};
#pragma unroll 1
    for (int ct = 0; ct < N / 16; ++ct) {
        floatx4 acc = {0.f, 0.f, 0.f, 0.f};
#pragma unroll
        for (int kk = 0; kk < K / 32; ++kk) {
            const bf16x8 bfrag =
                *(const bf16x8*)&Bt[(size_t)(ct * 16 + l16) * K + kk * 32 + quad * 8];
            acc = __builtin_amdgcn_mfma_f32_16x16x32_bf16(afrag[kk], bfrag, acc, 0, 0, 0);
        }
        const int gc = ct * 16 + l16;
        const int hh = gc >> 6;
        const int f = gc & 63;
        const float as = asrc[hh * 64 + f];
        const float ad = adst[hh * 64 + f];
#pragma unroll
        for (int rg = 0; rg < 4; ++rg) {
            sacc[rg] = fmaf(acc[rg], as, sacc[rg]);
            dacc[rg] = fmaf(acc[rg], ad, dacc[rg]);
        }
#pragma unroll
        for (int rg = 0; rg < 4; ++rg) {
            int gr = gr0 + rg;
            if (gr < rows) out[(size_t)gr * N + gc] = f2b(acc[rg]);
        }
        if ((ct & 3) == 3) {
#pragma unroll
            for (int rg = 0; rg < 4; ++rg) {
                float s = sacc[rg], d = dacc[rg];
                for (int o = 1; o < 16; o <<= 1) {
                    s += __shfl_xor(s, o);
                    d += __shfl_xor(d, o);
                }
                if (l16 == 0) {
                    int gr = gr0 + rg;
                    if (gr < rows) {
                        es[(size_t)gr * HEADS + hh] = s;
                        ed[(size_t)gr * HEADS + hh] = d;
                    }
                }
                sacc[rg] = 0.f;
                dacc[rg] = 0.f;
            }
        }
    }
}

// ---------------- GAT layer 1 FUSED with layer-2 projection GEMM ----------------
// 128-thread blocks (2 waves, 8 nodes; grid 6250 exact) -> 16 independent barrier
// groups per CU (vs 8 at 256 threads) so a block stalled at the phase boundary is
// covered by 15 others; wave-slot occupancy unchanged (32/CU).
// Phase 1 (proven round-0 structure): 16-lane group per dst node.
// Phase 2: block mini-GEMM 8x256 @ 256x64 via MFMA; A-frag rows 8-15 alias rows 0-7
// (t&7) and their duplicate D rows are not stored. Wave wv owns col-tiles wv*2..+1.
__global__ __launch_bounds__(128) void k_gat1f(
    const unsigned short* __restrict__ xW, const float* __restrict__ es, const float* __restrict__ ed,
    const int* __restrict__ offs, const int* __restrict__ deg, const int* __restrict__ csr,
    const int* __restrict__ perm, const float* __restrict__ bias,
    const unsigned short* __restrict__ Bt2, const float* __restrict__ as2,
    const float* __restrict__ ad2, unsigned short* __restrict__ outW,
    float* __restrict__ es2o, float* __restrict__ ed2o) {
    __shared__ float ps[2][4 * 68];          // [wave][grp*68 + j*4 + h]
    __shared__ int sbuf[2][64];              // [wave][grp*16 + j]
    __shared__ unsigned short As2[8 * 264];  // x1 bf16 rows (8 nodes), stride 264
    __shared__ int nbuf[8];
    __shared__ float sds[2][8], sdd[2][8];
    const int wv = threadIdx.x >> 6;
    const int lane = threadIdx.x & 63;
    const int grp = lane >> 4, t = lane & 15;
    const int h = t >> 2;
    const int r = wv * 4 + grp;                   // block-local row 0..7
    const int pidx = blockIdx.x * 8 + r;          // 6250*8 = 50000 exact
    const int n = perm[pidx];
    const int off = offs[n];
    const int dg = deg[n];
    const float4 edv = *(const float4*)&ed[n * 4];
    const int cb = t * 16;

    float acc[16];
#pragma unroll
    for (int k = 0; k < 16; ++k) acc[k] = 0.f;
    float dsum = 0.f;

    for (int base = 0; base < dg; base += 16) {
        const int idx = base + t;
        int s_l = 0;
        float p0 = 0.f, p1 = 0.f, p2 = 0.f, p3 = 0.f;
        if (idx < dg) {
            s_l = csr[off + idx];
            const float4 ev = *(const float4*)&es[s_l * 4];
            p0 = __expf(lrelu(ev.x + edv.x));
            p1 = __expf(lrelu(ev.y + edv.y));
            p2 = __expf(lrelu(ev.z + edv.z));
            p3 = __expf(lrelu(ev.w + edv.w));
        }
        *(float4*)&ps[wv][grp * 68 + t * 4] = make_float4(p0, p1, p2, p3);
        sbuf[wv][grp * 16 + t] = s_l;
        const int cnt = min(16, dg - base);
        const int cntR = (cnt + 3) & ~3;
        for (int j = 0; j < cntR; j += 4) {
            const float pa = ps[wv][grp * 68 + (j + 0) * 4 + h];
            const float pb = ps[wv][grp * 68 + (j + 1) * 4 + h];
            const float pc = ps[wv][grp * 68 + (j + 2) * 4 + h];
            const float pd = ps[wv][grp * 68 + (j + 3) * 4 + h];
            const int sa = sbuf[wv][grp * 16 + j + 0];
            const int sb = sbuf[wv][grp * 16 + j + 1];
            const int sc = sbuf[wv][grp * 16 + j + 2];
            const int sd = sbuf[wv][grp * 16 + j + 3];
            const uint4 a0 = *(const uint4*)&xW[(size_t)sa * 256 + cb];
            const uint4 a1 = *(const uint4*)&xW[(size_t)sa * 256 + cb + 8];
            const uint4 b0 = *(const uint4*)&xW[(size_t)sb * 256 + cb];
            const uint4 b1 = *(const uint4*)&xW[(size_t)sb * 256 + cb + 8];
            const uint4 c0 = *(const uint4*)&xW[(size_t)sc * 256 + cb];
            const uint4 c1 = *(const uint4*)&xW[(size_t)sc * 256 + cb + 8];
            const uint4 d0 = *(const uint4*)&xW[(size_t)sd * 256 + cb];
            const uint4 d1 = *(const uint4*)&xW[(size_t)sd * 256 + cb + 8];
            dsum += (pa + pb) + (pc + pd);
            acc[0]  = fmaf(pa, blo(a0.x), acc[0]);
            acc[1]  = fmaf(pa, bhi(a0.x), acc[1]);
            acc[2]  = fmaf(pa, blo(a0.y), acc[2]);
            acc[3]  = fmaf(pa, bhi(a0.y), acc[3]);
            acc[4]  = fmaf(pa, blo(a0.z), acc[4]);
            acc[5]  = fmaf(pa, bhi(a0.z), acc[5]);
            acc[6]  = fmaf(pa, blo(a0.w), acc[6]);
            acc[7]  = fmaf(pa, bhi(a0.w), acc[7]);
            acc[8]  = fmaf(pa, blo(a1.x), acc[8]);
            acc[9]  = fmaf(pa, bhi(a1.x), acc[9]);
            acc[10] = fmaf(pa, blo(a1.y), acc[10]);
            acc[11] = fmaf(pa, bhi(a1.y), acc[11]);
            acc[12] = fmaf(pa, blo(a1.z), acc[12]);
            acc[13] = fmaf(pa, bhi(a1.z), acc[13]);
            acc[14] = fmaf(pa, blo(a1.w), acc[14]);
            acc[15] = fmaf(pa, bhi(a1.w), acc[15]);
            acc[0]  = fmaf(pb, blo(b0.x), acc[0]);
            acc[1]  = fmaf(pb, bhi(b0.x), acc[1]);
            acc[2]  = fmaf(pb, blo(b0.y), acc[2]);
            acc[3]  = fmaf(pb, bhi(b0.y), acc[3]);
            acc[4]  = fmaf(pb, blo(b0.z), acc[4]);
            acc[5]  = fmaf(pb, bhi(b0.z), acc[5]);
            acc[6]  = fmaf(pb, blo(b0.w), acc[6]);
            acc[7]  = fmaf(pb, bhi(b0.w), acc[7]);
            acc[8]  = fmaf(pb, blo(b1.x), acc[8]);
            acc[9]  = fmaf(pb, bhi(b1.x), acc[9]);
            acc[10] = fmaf(pb, blo(b1.y), acc[10]);
            acc[11] = fmaf(pb, bhi(b1.y), acc[11]);
            acc[12] = fmaf(pb, blo(b1.z), acc[12]);
            acc[13] = fmaf(pb, bhi(b1.z), acc[13]);
            acc[14] = fmaf(pb, blo(b1.w), acc[14]);
            acc[15] = fmaf(pb, bhi(b1.w), acc[15]);
            acc[0]  = fmaf(pc, blo(c0.x), acc[0]);
            acc[1]  = fmaf(pc, bhi(c0.x), acc[1]);
            acc[2]  = fmaf(pc, blo(c0.y), acc[2]);
            acc[3]  = fmaf(pc, bhi(c0.y), acc[3]);
            acc[4]  = fmaf(pc, blo(c0.z), acc[4]);
            acc[5]  = fmaf(pc, bhi(c0.z), acc[5]);
            acc[6]  = fmaf(pc, blo(c0.w), acc[6]);
            acc[7]  = fmaf(pc, bhi(c0.w), acc[7]);
            acc[8]  = fmaf(pc, blo(c1.x), acc[8]);
            acc[9]  = fmaf(pc, bhi(c1.x), acc[9]);
            acc[10] = fmaf(pc, blo(c1.y), acc[10]);
            acc[11] = fmaf(pc, bhi(c1.y), acc[11]);
            acc[12] = fmaf(pc, blo(c1.z), acc[12]);
            acc[13] = fmaf(pc, bhi(c1.z), acc[13]);
            acc[14] = fmaf(pc, blo(c1.w), acc[14]);
            acc[15] = fmaf(pc, bhi(c1.w), acc[15]);
            acc[0]  = fmaf(pd, blo(d0.x), acc[0]);
            acc[1]  = fmaf(pd, bhi(d0.x), acc[1]);
            acc[2]  = fmaf(pd, blo(d0.y), acc[2]);
            acc[3]  = fmaf(pd, bhi(d0.y), acc[3]);
            acc[4]  = fmaf(pd, blo(d0.z), acc[4]);
            acc[5]  = fmaf(pd, bhi(d0.z), acc[5]);
            acc[6]  = fmaf(pd, blo(d0.w), acc[6]);
            acc[7]  = fmaf(pd, bhi(d0.w), acc[7]);
            acc[8]  = fmaf(pd, blo(d1.x), acc[8]);
            acc[9]  = fmaf(pd, bhi(d1.x), acc[9]);
            acc[10] = fmaf(pd, blo(d1.y), acc[10]);
            acc[11] = fmaf(pd, bhi(d1.y), acc[11]);
            acc[12] = fmaf(pd, blo(d1.z), acc[12]);
            acc[13] = fmaf(pd, bhi(d1.z), acc[13]);
            acc[14] = fmaf(pd, blo(d1.w), acc[14]);
            acc[15] = fmaf(pd, bhi(d1.w), acc[15]);
        }
    }
    // x1 row -> LDS (bf16, same rounding as the old x1b path)
    const float inv = 1.0f / fmaxf(dsum, 1e-16f);
#pragma unroll
    for (int k4 = 0; k4 < 16; k4 += 4) {
        const int c = cb + k4;
        const float4 bv = *(const float4*)&bias[c];
        ushort4 o4;
        o4.x = f2b(fmaxf(fmaf(acc[k4 + 0], inv, bv.x), 0.f));
        o4.y = f2b(fmaxf(fmaf(acc[k4 + 1], inv, bv.y), 0.f));
        o4.z = f2b(fmaxf(fmaf(acc[k4 + 2], inv, bv.z), 0.f));
        o4.w = f2b(fmaxf(fmaf(acc[k4 + 3], inv, bv.w), 0.f));
        *(ushort4*)&As2[r * 264 + c] = o4;
    }
    if (t == 0) nbuf[r] = n;
    __syncthreads();

    // Phase 2: 8x256 @ 256x64 mini-GEMM; wave wv owns col-tiles wv*2, wv*2+1.
    // A-frag row = t (rows 8-15 alias t&7 -> duplicate D rows, not stored).
    {
        float srg[4] = {0.f, 0.f, 0.f, 0.f};
        float drg[4] = {0.f, 0.f, 0.f, 0.f};
#pragma unroll
        for (int ci = 0; ci < 2; ++ci) {
            const int ct = wv * 2 + ci;
            const int gc = ct * 16 + t;
            floatx4 c2 = {0.f, 0.f, 0.f, 0.f};
#pragma unroll
            for (int kk = 0; kk < 8; ++kk) {
                const bf16x8 af = *(const bf16x8*)&As2[(t & 7) * 264 + kk * 32 + grp * 8];
                const bf16x8 bf = *(const bf16x8*)&Bt2[(size_t)gc * 256 + kk * 32 + grp * 8];
                c2 = __builtin_amdgcn_mfma_f32_16x16x32_bf16(af, bf, c2, 0, 0, 0);
            }
            const float a_s = as2[gc];
            const float a_d = ad2[gc];
#pragma unroll
            for (int rg = 0; rg < 4; ++rg) {
                srg[rg] = fmaf(c2[rg], a_s, srg[rg]);
                drg[rg] = fmaf(c2[rg], a_d, drg[rg]);
                const int row = grp * 4 + rg;  // D row; valid rows 0..7 (grp<2)
                if (grp < 2) outW[(size_t)nbuf[row] * 64 + gc] = f2b(c2[rg]);
            }
        }
#pragma unroll
        for (int rg = 0; rg < 4; ++rg) {
            for (int o = 1; o < 16; o <<= 1) {
                srg[rg] += __shfl_xor(srg[rg], o);
                drg[rg] += __shfl_xor(drg[rg], o);
            }
        }
        if (t == 0 && grp < 2) {
#pragma unroll
            for (int rg = 0; rg < 4; ++rg) {
                sds[wv][grp * 4 + rg] = srg[rg];
                sdd[wv][grp * 4 + rg] = drg[rg];
            }
        }
    }
    __syncthreads();
    if (threadIdx.x < 8) {
        const int rr = threadIdx.x;
        es2o[nbuf[rr]] = sds[0][rr] + sds[1][rr];
        ed2o[nbuf[rr]] = sdd[0][rr] + sdd[1][rr];
    }
}

// ---------------- GAT layers 2-3 FUSED with next-layer 64x64 GEMM ----------------
// 128-thread blocks (2 waves, 16 nodes; grid 3125 exact) -> 16 barrier groups/CU.
// Phase 1: proven gatL body (8-lane group/node). h row -> global fp32 + bf16 -> LDS.
// Phase 2: 16x64 @ 64x64 MFMA; wave wv owns col-tiles wv*2, wv*2+1.
template <bool RES>
__global__ __launch_bounds__(128) void k_gatLG(
    const unsigned short* __restrict__ xW, const float* __restrict__ es, const float* __restrict__ ed,
    const int* __restrict__ offs, const int* __restrict__ deg, const int* __restrict__ csr,
    const int* __restrict__ perm, const float* __restrict__ bias, const float* __restrict__ gam,
    const float* __restrict__ bet, float* __restrict__ hglob,
    const unsigned short* __restrict__ Btn, const float* __restrict__ asn,
    const float* __restrict__ adn, unsigned short* __restrict__ outW,
    float* __restrict__ esn, float* __restrict__ edn_o) {
    __shared__ float ps[2][64];
    __shared__ int sbuf[2][64];
    __shared__ unsigned short As2[16 * 72];  // h bf16 rows (16 nodes), stride 72
    __shared__ int nbuf[16];
    __shared__ float sds[2][16], sdd[2][16];
    const int wv = threadIdx.x >> 6;
    const int lane = threadIdx.x & 63;
    const int g8 = lane >> 3, t8 = lane & 7;
    const int row1 = wv * 8 + g8;               // block-local row 0..15
    const int pidx = blockIdx.x * 16 + row1;    // 3125*16 = 50000 exact
    const int n = perm[pidx];
    const int off = offs[n];
    const int dg = deg[n];
    const float edn = ed[n];
    const int cb = t8 * 8;

    float acc[8];
#pragma unroll
    for (int k = 0; k < 8; ++k) acc[k] = 0.f;
    float dsum = 0.f;

    for (int base = 0; base < dg; base += 8) {
        const int idx = base + t8;
        int s_l = 0;
        float p_l = 0.f;
        if (idx < dg) {
            s_l = csr[off + idx];
            p_l = __expf(lrelu(es[s_l] + edn));
        }
        ps[wv][g8 * 8 + t8] = p_l;
        sbuf[wv][g8 * 8 + t8] = s_l;
        float pp[8];
        int ss[8];
#pragma unroll
        for (int q = 0; q < 8; ++q) {
            pp[q] = ps[wv][g8 * 8 + q];
            ss[q] = sbuf[wv][g8 * 8 + q];
        }
        uint4 u[8];
#pragma unroll
        for (int q = 0; q < 8; ++q) u[q] = *(const uint4*)&xW[(size_t)ss[q] * 64 + cb];
#pragma unroll
        for (int q = 0; q < 8; ++q) {
            dsum += pp[q];
            acc[0] = fmaf(pp[q], blo(u[q].x), acc[0]);
            acc[1] = fmaf(pp[q], bhi(u[q].x), acc[1]);
            acc[2] = fmaf(pp[q], blo(u[q].y), acc[2]);
            acc[3] = fmaf(pp[q], bhi(u[q].y), acc[3]);
            acc[4] = fmaf(pp[q], blo(u[q].z), acc[4]);
            acc[5] = fmaf(pp[q], bhi(u[q].z), acc[5]);
            acc[6] = fmaf(pp[q], blo(u[q].w), acc[6]);
            acc[7] = fmaf(pp[q], bhi(u[q].w), acc[7]);
        }
    }
    const float inv = 1.0f / fmaxf(dsum, 1e-16f);
    float hn[8];
#pragma unroll
    for (int k = 0; k < 8; ++k) {
        const int c = cb + k;
        const float y = fmaf(acc[k], inv, bias[c]);
        const float z = fmaxf(fmaf(gam[c] * y, BN_RSQ, bet[c]), 0.f);
        hn[k] = RES ? hglob[(size_t)n * 64 + c] + z : z;
    }
    *(float4*)&hglob[(size_t)n * 64 + cb] = make_float4(hn[0], hn[1], hn[2], hn[3]);
    *(float4*)&hglob[(size_t)n * 64 + cb + 4] = make_float4(hn[4], hn[5], hn[6], hn[7]);
    ushort4 u0, u1;
    u0.x = f2b(hn[0]); u0.y = f2b(hn[1]); u0.z = f2b(hn[2]); u0.w = f2b(hn[3]);
    u1.x = f2b(hn[4]); u1.y = f2b(hn[5]); u1.z = f2b(hn[6]); u1.w = f2b(hn[7]);
    *(ushort4*)&As2[row1 * 72 + cb] = u0;
    *(ushort4*)&As2[row1 * 72 + cb + 4] = u1;
    if (t8 == 0) nbuf[row1] = n;
    __syncthreads();

    // Phase 2: 16x64 @ 64x64; wave wv owns col-tiles wv*2, wv*2+1
    {
        const int quad = lane >> 4, l16 = lane & 15;
        float sacc[4] = {0.f, 0.f, 0.f, 0.f};
        float dacc[4] = {0.f, 0.f, 0.f, 0.f};
#pragma unroll
        for (int ci = 0; ci < 2; ++ci) {
            const int ct = wv * 2 + ci;
            const int gc = ct * 16 + l16;
            floatx4 c2 = {0.f, 0.f, 0.f, 0.f};
#pragma unroll
            for (int kk = 0; kk < 2; ++kk) {
                const bf16x8 af = *(const bf16x8*)&As2[l16 * 72 + kk * 32 + quad * 8];
                const bf16x8 bf = *(const bf16x8*)&Btn[(size_t)gc * 64 + kk * 32 + quad * 8];
                c2 = __builtin_amdgcn_mfma_f32_16x16x32_bf16(af, bf, c2, 0, 0, 0);
            }
            const float a_s = asn[gc];
            const float a_d = adn[gc];
#pragma unroll
            for (int rg = 0; rg < 4; ++rg) {
                sacc[rg] = fmaf(c2[rg], a_s, sacc[rg]);
                dacc[rg] = fmaf(c2[rg], a_d, dacc[rg]);
                const int row = quad * 4 + rg;
                outW[(size_t)nbuf[row] * 64 + gc] = f2b(c2[rg]);
            }
        }
#pragma unroll
        for (int rg = 0; rg < 4; ++rg) {
            for (int o = 1; o < 16; o <<= 1) {
                sacc[rg] += __shfl_xor(sacc[rg], o);
                dacc[rg] += __shfl_xor(dacc[rg], o);
            }
        }
        if (l16 == 0) {
#pragma unroll
            for (int rg = 0; rg < 4; ++rg) {
                sds[wv][quad * 4 + rg] = sacc[rg];
                sdd[wv][quad * 4 + rg] = dacc[rg];
            }
        }
    }
    __syncthreads();
    if (threadIdx.x < 16) {
        const int rr = threadIdx.x;
        esn[nbuf[rr]] = sds[0][rr] + sds[1][rr];
        edn_o[nbuf[rr]] = sdd[0][rr] + sdd[1][rr];
    }
}

// ---------------- final GAT layer (residual, no next GEMM, no bf16 out) ----------------
__global__ __launch_bounds__(256) void k_gatF(
    const unsigned short* __restrict__ xW, const float* __restrict__ es, const float* __restrict__ ed,
    const int* __restrict__ offs, const int* __restrict__ deg, const int* __restrict__ csr,
    const int* __restrict__ perm, const float* __restrict__ bias, const float* __restrict__ gam,
    const float* __restrict__ bet, float* __restrict__ h) {
    __shared__ float ps[4][64];
    __shared__ int sbuf[4][64];
    const int wv = threadIdx.x >> 6;
    const int lane = threadIdx.x & 63;
    const int grp = lane >> 3, t = lane & 7;
    const int pidx = blockIdx.x * 32 + wv * 8 + grp;
    if (pidx >= N_NODES) return;
    const int n = perm[pidx];
    const int off = offs[n];
    const int dg = deg[n];
    const float edn = ed[n];
    const int cb = t * 8;

    float acc[8];
#pragma unroll
    for (int k = 0; k < 8; ++k) acc[k] = 0.f;
    float dsum = 0.f;

    for (int base = 0; base < dg; base += 8) {
        const int idx = base + t;
        int s_l = 0;
        float p_l = 0.f;
        if (idx < dg) {
            s_l = csr[off + idx];
            p_l = __expf(lrelu(es[s_l] + edn));
        }
        ps[wv][grp * 8 + t] = p_l;
        sbuf[wv][grp * 8 + t] = s_l;
        float pp[8];
        int ss[8];
#pragma unroll
        for (int q = 0; q < 8; ++q) {
            pp[q] = ps[wv][grp * 8 + q];
            ss[q] = sbuf[wv][grp * 8 + q];
        }
        uint4 u[8];
#pragma unroll
        for (int q = 0; q < 8; ++q) u[q] = *(const uint4*)&xW[(size_t)ss[q] * 64 + cb];
#pragma unroll
        for (int q = 0; q < 8; ++q) {
            dsum += pp[q];
            acc[0] = fmaf(pp[q], blo(u[q].x), acc[0]);
            acc[1] = fmaf(pp[q], bhi(u[q].x), acc[1]);
            acc[2] = fmaf(pp[q], blo(u[q].y), acc[2]);
            acc[3] = fmaf(pp[q], bhi(u[q].y), acc[3]);
            acc[4] = fmaf(pp[q], blo(u[q].z), acc[4]);
            acc[5] = fmaf(pp[q], bhi(u[q].z), acc[5]);
            acc[6] = fmaf(pp[q], blo(u[q].w), acc[6]);
            acc[7] = fmaf(pp[q], bhi(u[q].w), acc[7]);
        }
    }
    const float inv = 1.0f / fmaxf(dsum, 1e-16f);
    float hn[8];
#pragma unroll
    for (int k = 0; k < 8; ++k) {
        const int c = cb + k;
        const float y = fmaf(acc[k], inv, bias[c]);
        const float z = fmaxf(fmaf(gam[c] * y, BN_RSQ, bet[c]), 0.f);
        hn[k] = h[(size_t)n * 64 + c] + z;
    }
    *(float4*)&h[(size_t)n * 64 + cb] = make_float4(hn[0], hn[1], hn[2], hn[3]);
    *(float4*)&h[(size_t)n * 64 + cb + 4] = make_float4(hn[4], hn[5], hn[6], hn[7]);
}

// ---------------- mean pool: one block per graph ----------------
__global__ __launch_bounds__(256) void k_pool2(const float* __restrict__ h,
                                               const int* __restrict__ bounds,
                                               float* __restrict__ hp) {
    __shared__ float part[4][64];
    const int g = blockIdx.x;
    const int lane = threadIdx.x & 63;
    const int wid = threadIdx.x >> 6;
    const int s = bounds[g], e = bounds[g + 1];
    float acc = 0.f;
    for (int n = s + wid; n < e; n += 4) acc += h[n * 64 + lane];
    part[wid][lane] = acc;
    __syncthreads();
    if (wid == 0) {
        float v = part[0][lane] + part[1][lane] + part[2][lane] + part[3][lane];
        hp[g * 64 + lane] = v / fmaxf((float)(e - s), 1.0f);
    }
}

// ---------------- MLP head, single block ----------------
__global__ __launch_bounds__(256) void k_head(const float* __restrict__ hpg,
                                              const float* __restrict__ Wh1,
                                              const float* __restrict__ bh1,
                                              const float* __restrict__ Wh2,
                                              const float* __restrict__ bh2,
                                              float* __restrict__ out) {
    __shared__ float hp[64 * 64];
    __shared__ float t1[64 * 128];
    const int tid = threadIdx.x;
    for (int i = tid; i < 64 * 64; i += 256) hp[i] = hpg[i];
    __syncthreads();
    for (int i = tid; i < 64 * 128; i += 256) {
        int g = i >> 7, j = i & 127;
        float s = bh1[j];
        for (int k = 0; k < 64; ++k) s = fmaf(hp[g * 64 + k], Wh1[k * 128 + j], s);
        t1[i] = fmaxf(s, 0.f);
    }
    __syncthreads();
    for (int i = tid; i < 640; i += 256) {
        int g = i / 10, j = i - g * 10;
        float s = bh2[j];
        for (int k = 0; k < 128; ++k) s = fmaf(t1[g * 128 + k], Wh2[k * 10 + j], s);
        out[i] = s;
    }
}

extern "C" void kernel_launch(void* const* d_in, const int* in_sizes, int n_in,
                              void* d_out, int out_size, void* d_ws, size_t ws_size,
                              hipStream_t stream) {
    const float* x = (const float*)d_in[1];
    const int* ei = (const int*)d_in[2];
    const int* batch = (const int*)d_in[3];
    const float* W1 = (const float*)d_in[4];
    const float* a_src1 = (const float*)d_in[5];
    const float* a_dst1 = (const float*)d_in[6];
    const float* b1 = (const float*)d_in[7];
    const float* W2 = (const float*)d_in[8];
    const float* a_src2 = (const float*)d_in[9];
    const float* a_dst2 = (const float*)d_in[10];
    const float* b2 = (const float*)d_in[11];
    const float* g2 = (const float*)d_in[12];
    const float* be2 = (const float*)d_in[13];
    const float* W3 = (const float*)d_in[14];
    const float* a_src3 = (const float*)d_in[15];
    const float* a_dst3 = (const float*)d_in[16];
    const float* b3 = (const float*)d_in[17];
    const float* g3 = (const float*)d_in[18];
    const float* be3 = (const float*)d_in[19];
    const float* W4 = (const float*)d_in[20];
    const float* a_src4 = (const float*)d_in[21];
    const float* a_dst4 = (const float*)d_in[22];
    const float* b4 = (const float*)d_in[23];
    const float* g4 = (const float*)d_in[24];
    const float* be4 = (const float*)d_in[25];
    const float* Wh1 = (const float*)d_in[26];
    const float* bh1 = (const float*)d_in[27];
    const float* Wh2 = (const float*)d_in[28];
    const float* bh2 = (const float*)d_in[29];
    float* out = (float*)d_out;

    // workspace layout
    char* p = (char*)d_ws;
    auto alloc = [&](size_t bytes) {
        void* r = (void*)p;
        p += (bytes + 255) & ~(size_t)255;
        return r;
    };
    unsigned short* bufA1 = (unsigned short*)alloc((size_t)N_NODES * 256 * 2);  // xW1 bf16
    unsigned short* bufB = (unsigned short*)alloc((size_t)N_NODES * 64 * 2);    // xW2 bf16
    unsigned short* bufC = (unsigned short*)alloc((size_t)N_NODES * 64 * 2);    // xW3 bf16
    unsigned short* bufD = (unsigned short*)alloc((size_t)N_NODES * 64 * 2);    // xW4 bf16
    float* h = (float*)alloc((size_t)N_NODES * 64 * 4);                         // h fp32
    float* es1 = (float*)alloc((size_t)N_NODES * 4 * 4);
    float* ed1 = (float*)alloc((size_t)N_NODES * 4 * 4);
    float* es2 = (float*)alloc((size_t)N_NODES * 4);
    float* ed2 = (float*)alloc((size_t)N_NODES * 4);
    float* es3 = (float*)alloc((size_t)N_NODES * 4);
    float* ed3 = (float*)alloc((size_t)N_NODES * 4);
    float* es4 = (float*)alloc((size_t)N_NODES * 4);
    float* ed4 = (float*)alloc((size_t)N_NODES * 4);
    int* offs = (int*)alloc((size_t)N_NODES * 4);
    int* csr = (int*)alloc((size_t)N_EDGES * 4);
    int* perm = (int*)alloc((size_t)N_NODES * 4);
    int* bounds = (int*)alloc((size_t)(N_GRAPHS + 1) * 4);
    int* bh_hist = (int*)alloc((size_t)NB_SCAN * 64 * 4);
    int* bb = (int*)alloc((size_t)NB_SCAN * 64 * 4);
    float* hpool = (float*)alloc((size_t)N_GRAPHS * 64 * 4);
    unsigned short* Wt1 = (unsigned short*)alloc((size_t)128 * 256 * 2);
    unsigned short* Wt2 = (unsigned short*)alloc((size_t)256 * 64 * 2);
    unsigned short* Wt3 = (unsigned short*)alloc((size_t)64 * 64 * 2);
    unsigned short* Wt4 = (unsigned short*)alloc((size_t)64 * 64 * 2);
    char* z0 = p;  // everything below gets zeroed each call
    int* deg = (int*)alloc((size_t)N_NODES * 4);
    int* cur = (int*)alloc((size_t)N_NODES * 4);
    int* total = (int*)alloc(256);
    size_t zbytes = (size_t)(p - z0);
    hipMemsetAsync(z0, 0, zbytes, stream);

    const int edgeBlocks = (N_EDGES + 255) / 256;
    const int mgemmBlocks = (N_NODES + 63) / 64;
    const int gat1Blocks = N_NODES / 8;    // 6250 exact, 128-thread blocks
    const int gatLGBlocks = N_NODES / 16;  // 3125 exact, 128-thread blocks
    const int gatFBlocks = (N_NODES + 31) / 32;

    // fused prep: degree count + weight bf16 transposes
    k_prep<<<edgeBlocks, 256, 0, stream>>>(ei, deg, W1, W2, W3, W4, Wt1, Wt2, Wt3, Wt4);

    // CSR offsets + LPT histogram + graph bounds; bucket scan; merged fill+perm
    k_offs<<<NB_SCAN, 256, 0, stream>>>(deg, offs, total, batch, bounds, bh_hist);
    k_pscan<<<1, 256, 0, stream>>>(bh_hist, bb);
    k_fillperm<<<edgeBlocks, 256, 0, stream>>>(ei, offs, cur, csr, deg, bb, perm);

    // layer 1 GEMM: xW1 + attention dots
    k_mgemm<128, 256, 4, true><<<mgemmBlocks, 256, 0, stream>>>(x, Wt1, a_src1, a_dst1,
                                                                bufA1, es1, ed1, N_NODES);
    // layer 1 gather + FUSED layer-2 projection GEMM (x1 never hits HBM)
    k_gat1f<<<gat1Blocks, 128, 0, stream>>>(bufA1, es1, ed1, offs, deg, csr, perm, b1,
                                            Wt2, a_src2, a_dst2, bufB, es2, ed2);

    // layer 2 gather + BN + relu + FUSED layer-3 GEMM
    k_gatLG<false><<<gatLGBlocks, 128, 0, stream>>>(bufB, es2, ed2, offs, deg, csr, perm,
                                                    b2, g2, be2, h, Wt3, a_src3, a_dst3,
                                                    bufC, es3, ed3);
    // layer 3 residual gather + FUSED layer-4 GEMM
    k_gatLG<true><<<gatLGBlocks, 128, 0, stream>>>(bufC, es3, ed3, offs, deg, csr, perm,
                                                   b3, g3, be3, h, Wt4, a_src4, a_dst4,
                                                   bufD, es4, ed4);
    // layer 4 residual gather (final)
    k_gatF<<<gatFBlocks, 256, 0, stream>>>(bufD, es4, ed4, offs, deg, csr, perm, b4, g4, be4, h);

    // pool + head (batch sorted -> contiguous ranges, no atomics)
    k_pool2<<<N_GRAPHS, 256, 0, stream>>>(h, bounds, hpool);
    k_head<<<1, 256, 0, stream>>>(hpool, Wh1, bh1, Wh2, bh2, out);
}

// Round 8
// 483.092 us; speedup vs baseline: 1.1274x; 1.0498x over previous
//
#include <hip/hip_runtime.h>

#define N_NODES 50000
#define N_EDGES 800000
#define N_GRAPHS 64
#define NEG_SLOPE 0.2f
// 1/sqrt(1 + 1e-5), BN eval-mode scale
#define BN_RSQ 0.9999950000374997f
#define NB_SCAN ((N_NODES + 255) / 256)  // 196 blocks in the node-space scan

typedef __bf16 bf16x8 __attribute__((ext_vector_type(8)));
typedef float floatx4 __attribute__((ext_vector_type(4)));

__device__ __forceinline__ float lrelu(float v) { return v > 0.0f ? v : NEG_SLOPE * v; }

// bf16 <-> f32 (round-to-nearest-even)
__device__ __forceinline__ float b2f(unsigned short u) {
    return __uint_as_float(((unsigned int)u) << 16);
}
__device__ __forceinline__ unsigned short f2b(float f) {
    unsigned int u = __float_as_uint(f);
    return (unsigned short)((u + 0x7fffu + ((u >> 16) & 1u)) >> 16);
}
// unpack 2 bf16 from one dword (1 instr each: shl / and)
__device__ __forceinline__ float blo(unsigned int d) { return __uint_as_float(d << 16); }
__device__ __forceinline__ float bhi(unsigned int d) { return __uint_as_float(d & 0xffff0000u); }

// ---------------- fused prep: degree count + weight bf16 transpose (all layers) ----------------
// Wt[n*K+k] = bf16(W[k*N+n]) — MFMA B-fragment layout.
__global__ void k_prep(const int* __restrict__ ei, int* __restrict__ deg,
                       const float* __restrict__ W1, const float* __restrict__ W2,
                       const float* __restrict__ W3, const float* __restrict__ W4,
                       unsigned short* __restrict__ Wt1, unsigned short* __restrict__ Wt2,
                       unsigned short* __restrict__ Wt3, unsigned short* __restrict__ Wt4) {
    int i = blockIdx.x * 256 + threadIdx.x;
    if (i < 32768) {  // W1: 128x256
        int k = i >> 8, n = i & 255;
        Wt1[n * 128 + k] = f2b(W1[i]);
    } else if (i < 49152) {  // W2: 256x64
        int j = i - 32768;
        int k = j >> 6, n = j & 63;
        Wt2[n * 256 + k] = f2b(W2[j]);
    } else if (i < 53248) {  // W3: 64x64
        int j = i - 49152;
        int k = j >> 6, n = j & 63;
        Wt3[n * 64 + k] = f2b(W3[j]);
    } else if (i < 57344) {  // W4: 64x64
        int j = i - 53248;
        int k = j >> 6, n = j & 63;
        Wt4[n * 64 + k] = f2b(W4[j]);
    }
    if (i < N_EDGES) atomicAdd(&deg[ei[N_EDGES + i]], 1);
}

// offsets via wave shuffle-scan + one atomic per wave; per-block degree histogram
// (LPT: bucket = 63 - min(deg,63) -> descending-degree sort); graph bounds.
__global__ __launch_bounds__(256) void k_offs(const int* __restrict__ deg, int* __restrict__ offs,
                                              int* __restrict__ total, const int* __restrict__ batch,
                                              int* __restrict__ bounds, int* __restrict__ bh) {
    __shared__ int lh[64];
    if (threadIdx.x < 64) lh[threadIdx.x] = 0;
    __syncthreads();
    if (blockIdx.x == 0 && threadIdx.x <= N_GRAPHS) {
        int g = threadIdx.x;
        int lo = 0, hi = N_NODES;
        while (lo < hi) {
            int mid = (lo + hi) >> 1;
            if (batch[mid] < g) lo = mid + 1; else hi = mid;
        }
        bounds[g] = lo;
    }
    int i = blockIdx.x * blockDim.x + threadIdx.x;
    int lane = threadIdx.x & 63;
    int v = (i < N_NODES) ? deg[i] : 0;
    int incl = v;
    for (int o = 1; o < 64; o <<= 1) {
        int t = __shfl_up(incl, o);
        if (lane >= o) incl += t;
    }
    int wtot = __shfl(incl, 63);
    int base = 0;
    if (lane == 0) base = atomicAdd(total, wtot);
    base = __shfl(base, 0);
    if (i < N_NODES) {
        offs[i] = base + incl - v;
        atomicAdd(&lh[63 - min(v, 63)], 1);  // LDS atomic, block-local; LPT flip
    }
    __syncthreads();
    if (threadIdx.x < 64) bh[blockIdx.x * 64 + threadIdx.x] = lh[threadIdx.x];
}

// single block: bucket totals -> exclusive bucket scan -> per-block bucket bases
__global__ __launch_bounds__(256) void k_pscan(const int* __restrict__ bh, int* __restrict__ bb) {
    __shared__ int partial[4][64];
    __shared__ int bbase[64];
    const int tid = threadIdx.x;
    const int b = tid & 63, q = tid >> 6;
    const int per = (NB_SCAN + 3) / 4;
    const int k0 = q * per, k1 = min(k0 + per, NB_SCAN);
    int s = 0;
    for (int k = k0; k < k1; ++k) s += bh[k * 64 + b];
    partial[q][b] = s;
    __syncthreads();
    if (tid < 64) {
        int tot = partial[0][tid] + partial[1][tid] + partial[2][tid] + partial[3][tid];
        int incl = tot;
        for (int o = 1; o < 64; o <<= 1) {
            int t2 = __shfl_up(incl, o);
            if (tid >= o) incl += t2;
        }
        bbase[tid] = incl - tot;
    }
    __syncthreads();
    int run = bbase[b];
    for (int q2 = 0; q2 < q; ++q2) run += partial[q2][b];
    for (int k = k0; k < k1; ++k) {
        bb[k * 64 + b] = run;
        run += bh[k * 64 + b];
    }
}

// merged: CSR fill (edge-space) + degree-sort scatter (first NB_SCAN blocks)
__global__ __launch_bounds__(256) void k_fillperm(const int* __restrict__ ei,
                                                  const int* __restrict__ offs,
                                                  int* __restrict__ cur, int* __restrict__ csr_src,
                                                  const int* __restrict__ deg,
                                                  const int* __restrict__ bb,
                                                  int* __restrict__ perm) {
    __shared__ int lcnt[64];
    if (blockIdx.x < NB_SCAN) {  // block-uniform branch: barrier is safe
        if (threadIdx.x < 64) lcnt[threadIdx.x] = 0;
        __syncthreads();
        int i = blockIdx.x * 256 + threadIdx.x;
        if (i < N_NODES) {
            int b = 63 - min(deg[i], 63);  // LPT flip
            int r = atomicAdd(&lcnt[b], 1);
            perm[bb[blockIdx.x * 64 + b] + r] = i;
        }
    }
    int e = blockIdx.x * 256 + threadIdx.x;
    if (e < N_EDGES) {
        int d = ei[N_EDGES + e];
        int pos = offs[d] + atomicAdd(&cur[d], 1);
        csr_src[pos] = ei[e];
    }
}

// ---------------- MFMA GEMM + fused attention dots (layer 1 only) ----------------
// C/D layout (m89-verified): row=quad*4+rg, col=ct*16+l16.
template <int K, int N, int HEADS, bool AF32>
__global__ __launch_bounds__(256) void k_mgemm(const void* __restrict__ Ap,
                                               const unsigned short* __restrict__ Bt,
                                               const float* __restrict__ asrc,
                                               const float* __restrict__ adst,
                                               unsigned short* __restrict__ out,
                                               float* __restrict__ es,
                                               float* __restrict__ ed, int rows) {
    constexpr int LDP = K + 8;
    __shared__ unsigned short As[64 * LDP];
    const int tid = threadIdx.x;
    const int r0 = blockIdx.x * 64;
    if (AF32) {
        const float* A = (const float*)Ap;
        for (int i = tid; i < 16 * K; i += 256) {
            int r = i / (K / 4), c4 = i % (K / 4);
            int row = r0 + r;
            float4 v = (row < rows) ? *(const float4*)&A[(size_t)row * K + c4 * 4]
                                    : make_float4(0.f, 0.f, 0.f, 0.f);
            ushort4 u;
            u.x = f2b(v.x); u.y = f2b(v.y); u.z = f2b(v.z); u.w = f2b(v.w);
            *(ushort4*)&As[r * LDP + c4 * 4] = u;
        }
    } else {
        const unsigned short* A = (const unsigned short*)Ap;
        for (int i = tid; i < 8 * K; i += 256) {
            int r = i / (K / 8), c8 = i % (K / 8);
            int row = r0 + r;
            uint4 v;
            if (row < rows) v = *(const uint4*)&A[(size_t)row * K + c8 * 8];
            else { v.x = v.y = v.z = v.w = 0; }
            *(uint4*)&As[r * LDP + c8 * 8] = v;
        }
    }
    __syncthreads();
    const int w = tid >> 6, lane = tid & 63;
    const int quad = lane >> 4, l16 = lane & 15;
    const int gr0 = r0 + w * 16 + quad * 4;
    bf16x8 afrag[K / 32];
#pragma unroll
    for (int kk = 0; kk < K / 32; ++kk)
        afrag[kk] = *(const bf16x8*)&As[(w * 16 + l16) * LDP + kk * 32 + quad * 8];
    float sacc[4] = {0.f, 0.f, 0.f, 0.f};
    float dacc[4] = {0.f, 0.f, 0.f, 0.f};
#pragma unroll 1
    for (int ct = 0; ct < N / 16; ++ct) {
        floatx4 acc = {0.f, 0.f, 0.f, 0.f};
#pragma unroll
        for (int kk = 0; kk < K / 32; ++kk) {
            const bf16x8 bfrag =
                *(const bf16x8*)&Bt[(size_t)(ct * 16 + l16) * K + kk * 32 + quad * 8];
            acc = __builtin_amdgcn_mfma_f32_16x16x32_bf16(afrag[kk], bfrag, acc, 0, 0, 0);
        }
        const int gc = ct * 16 + l16;
        const int hh = gc >> 6;
        const int f = gc & 63;
        const float as = asrc[hh * 64 + f];
        const float ad = adst[hh * 64 + f];
#pragma unroll
        for (int rg = 0; rg < 4; ++rg) {
            sacc[rg] = fmaf(acc[rg], as, sacc[rg]);
            dacc[rg] = fmaf(acc[rg], ad, dacc[rg]);
        }
#pragma unroll
        for (int rg = 0; rg < 4; ++rg) {
            int gr = gr0 + rg;
            if (gr < rows) out[(size_t)gr * N + gc] = f2b(acc[rg]);
        }
        if ((ct & 3) == 3) {
#pragma unroll
            for (int rg = 0; rg < 4; ++rg) {
                float s = sacc[rg], d = dacc[rg];
                for (int o = 1; o < 16; o <<= 1) {
                    s += __shfl_xor(s, o);
                    d += __shfl_xor(d, o);
                }
                if (l16 == 0) {
                    int gr = gr0 + rg;
                    if (gr < rows) {
                        es[(size_t)gr * HEADS + hh] = s;
                        ed[(size_t)gr * HEADS + hh] = d;
                    }
                }
                sacc[rg] = 0.f;
                dacc[rg] = 0.f;
            }
        }
    }
}

// ---------------- GAT layer 1 FUSED with layer-2 projection GEMM ----------------
// Round-4 form (measured 72.9us): 256 threads, 16-lane group per dst node, 4 nodes/
// wave, 16 nodes/block (grid 3125 exact). Full 16-row A-frag in phase 2 (no waste);
// 128-thread variant (round 7) halved A-frag utilization and regressed to 83.5us.
// Phase 2: block mini-GEMM 16x256 @ 256x64 (Wt2) via MFMA; wave w owns col-tile w.
__global__ __launch_bounds__(256) void k_gat1f(
    const unsigned short* __restrict__ xW, const float* __restrict__ es, const float* __restrict__ ed,
    const int* __restrict__ offs, const int* __restrict__ deg, const int* __restrict__ csr,
    const int* __restrict__ perm, const float* __restrict__ bias,
    const unsigned short* __restrict__ Bt2, const float* __restrict__ as2,
    const float* __restrict__ ad2, unsigned short* __restrict__ outW,
    float* __restrict__ es2o, float* __restrict__ ed2o) {
    __shared__ float ps[4][4 * 68];          // [wave][grp*68 + j*4 + h]
    __shared__ int sbuf[4][64];              // [wave][grp*16 + j]
    __shared__ unsigned short As2[16 * 264]; // x1 bf16 rows, LDP2=264
    __shared__ int nbuf[16];
    __shared__ float sds[4][16], sdd[4][16];
    const int wv = threadIdx.x >> 6;
    const int lane = threadIdx.x & 63;
    const int grp = lane >> 4, t = lane & 15;
    const int h = t >> 2;
    const int r = wv * 4 + grp;                    // block-local row 0..15
    const int pidx = blockIdx.x * 16 + r;          // 3125*16 = 50000 exact
    const int n = perm[pidx];
    const int off = offs[n];
    const int dg = deg[n];
    const float4 edv = *(const float4*)&ed[n * 4];
    const int cb = t * 16;

    float acc[16];
#pragma unroll
    for (int k = 0; k < 16; ++k) acc[k] = 0.f;
    float dsum = 0.f;

    for (int base = 0; base < dg; base += 16) {
        const int idx = base + t;
        int s_l = 0;
        float p0 = 0.f, p1 = 0.f, p2 = 0.f, p3 = 0.f;
        if (idx < dg) {
            s_l = csr[off + idx];
            const float4 ev = *(const float4*)&es[s_l * 4];
            p0 = __expf(lrelu(ev.x + edv.x));
            p1 = __expf(lrelu(ev.y + edv.y));
            p2 = __expf(lrelu(ev.z + edv.z));
            p3 = __expf(lrelu(ev.w + edv.w));
        }
        *(float4*)&ps[wv][grp * 68 + t * 4] = make_float4(p0, p1, p2, p3);
        sbuf[wv][grp * 16 + t] = s_l;
        const int cnt = min(16, dg - base);
        const int cntR = (cnt + 3) & ~3;
        for (int j = 0; j < cntR; j += 4) {
            const float pa = ps[wv][grp * 68 + (j + 0) * 4 + h];
            const float pb = ps[wv][grp * 68 + (j + 1) * 4 + h];
            const float pc = ps[wv][grp * 68 + (j + 2) * 4 + h];
            const float pd = ps[wv][grp * 68 + (j + 3) * 4 + h];
            const int sa = sbuf[wv][grp * 16 + j + 0];
            const int sb = sbuf[wv][grp * 16 + j + 1];
            const int sc = sbuf[wv][grp * 16 + j + 2];
            const int sd = sbuf[wv][grp * 16 + j + 3];
            const uint4 a0 = *(const uint4*)&xW[(size_t)sa * 256 + cb];
            const uint4 a1 = *(const uint4*)&xW[(size_t)sa * 256 + cb + 8];
            const uint4 b0 = *(const uint4*)&xW[(size_t)sb * 256 + cb];
            const uint4 b1 = *(const uint4*)&xW[(size_t)sb * 256 + cb + 8];
            const uint4 c0 = *(const uint4*)&xW[(size_t)sc * 256 + cb];
            const uint4 c1 = *(const uint4*)&xW[(size_t)sc * 256 + cb + 8];
            const uint4 d0 = *(const uint4*)&xW[(size_t)sd * 256 + cb];
            const uint4 d1 = *(const uint4*)&xW[(size_t)sd * 256 + cb + 8];
            dsum += (pa + pb) + (pc + pd);
            acc[0]  = fmaf(pa, blo(a0.x), acc[0]);
            acc[1]  = fmaf(pa, bhi(a0.x), acc[1]);
            acc[2]  = fmaf(pa, blo(a0.y), acc[2]);
            acc[3]  = fmaf(pa, bhi(a0.y), acc[3]);
            acc[4]  = fmaf(pa, blo(a0.z), acc[4]);
            acc[5]  = fmaf(pa, bhi(a0.z), acc[5]);
            acc[6]  = fmaf(pa, blo(a0.w), acc[6]);
            acc[7]  = fmaf(pa, bhi(a0.w), acc[7]);
            acc[8]  = fmaf(pa, blo(a1.x), acc[8]);
            acc[9]  = fmaf(pa, bhi(a1.x), acc[9]);
            acc[10] = fmaf(pa, blo(a1.y), acc[10]);
            acc[11] = fmaf(pa, bhi(a1.y), acc[11]);
            acc[12] = fmaf(pa, blo(a1.z), acc[12]);
            acc[13] = fmaf(pa, bhi(a1.z), acc[13]);
            acc[14] = fmaf(pa, blo(a1.w), acc[14]);
            acc[15] = fmaf(pa, bhi(a1.w), acc[15]);
            acc[0]  = fmaf(pb, blo(b0.x), acc[0]);
            acc[1]  = fmaf(pb, bhi(b0.x), acc[1]);
            acc[2]  = fmaf(pb, blo(b0.y), acc[2]);
            acc[3]  = fmaf(pb, bhi(b0.y), acc[3]);
            acc[4]  = fmaf(pb, blo(b0.z), acc[4]);
            acc[5]  = fmaf(pb, bhi(b0.z), acc[5]);
            acc[6]  = fmaf(pb, blo(b0.w), acc[6]);
            acc[7]  = fmaf(pb, bhi(b0.w), acc[7]);
            acc[8]  = fmaf(pb, blo(b1.x), acc[8]);
            acc[9]  = fmaf(pb, bhi(b1.x), acc[9]);
            acc[10] = fmaf(pb, blo(b1.y), acc[10]);
            acc[11] = fmaf(pb, bhi(b1.y), acc[11]);
            acc[12] = fmaf(pb, blo(b1.z), acc[12]);
            acc[13] = fmaf(pb, bhi(b1.z), acc[13]);
            acc[14] = fmaf(pb, blo(b1.w), acc[14]);
            acc[15] = fmaf(pb, bhi(b1.w), acc[15]);
            acc[0]  = fmaf(pc, blo(c0.x), acc[0]);
            acc[1]  = fmaf(pc, bhi(c0.x), acc[1]);
            acc[2]  = fmaf(pc, blo(c0.y), acc[2]);
            acc[3]  = fmaf(pc, bhi(c0.y), acc[3]);
            acc[4]  = fmaf(pc, blo(c0.z), acc[4]);
            acc[5]  = fmaf(pc, bhi(c0.z), acc[5]);
            acc[6]  = fmaf(pc, blo(c0.w), acc[6]);
            acc[7]  = fmaf(pc, bhi(c0.w), acc[7]);
            acc[8]  = fmaf(pc, blo(c1.x), acc[8]);
            acc[9]  = fmaf(pc, bhi(c1.x), acc[9]);
            acc[10] = fmaf(pc, blo(c1.y), acc[10]);
            acc[11] = fmaf(pc, bhi(c1.y), acc[11]);
            acc[12] = fmaf(pc, blo(c1.z), acc[12]);
            acc[13] = fmaf(pc, bhi(c1.z), acc[13]);
            acc[14] = fmaf(pc, blo(c1.w), acc[14]);
            acc[15] = fmaf(pc, bhi(c1.w), acc[15]);
            acc[0]  = fmaf(pd, blo(d0.x), acc[0]);
            acc[1]  = fmaf(pd, bhi(d0.x), acc[1]);
            acc[2]  = fmaf(pd, blo(d0.y), acc[2]);
            acc[3]  = fmaf(pd, bhi(d0.y), acc[3]);
            acc[4]  = fmaf(pd, blo(d0.z), acc[4]);
            acc[5]  = fmaf(pd, bhi(d0.z), acc[5]);
            acc[6]  = fmaf(pd, blo(d0.w), acc[6]);
            acc[7]  = fmaf(pd, bhi(d0.w), acc[7]);
            acc[8]  = fmaf(pd, blo(d1.x), acc[8]);
            acc[9]  = fmaf(pd, bhi(d1.x), acc[9]);
            acc[10] = fmaf(pd, blo(d1.y), acc[10]);
            acc[11] = fmaf(pd, bhi(d1.y), acc[11]);
            acc[12] = fmaf(pd, blo(d1.z), acc[12]);
            acc[13] = fmaf(pd, bhi(d1.z), acc[13]);
            acc[14] = fmaf(pd, blo(d1.w), acc[14]);
            acc[15] = fmaf(pd, bhi(d1.w), acc[15]);
        }
    }
    // x1 row -> LDS (bf16, same rounding as the old x1b path)
    const float inv = 1.0f / fmaxf(dsum, 1e-16f);
#pragma unroll
    for (int k4 = 0; k4 < 16; k4 += 4) {
        const int c = cb + k4;
        const float4 bv = *(const float4*)&bias[c];
        ushort4 o4;
        o4.x = f2b(fmaxf(fmaf(acc[k4 + 0], inv, bv.x), 0.f));
        o4.y = f2b(fmaxf(fmaf(acc[k4 + 1], inv, bv.y), 0.f));
        o4.z = f2b(fmaxf(fmaf(acc[k4 + 2], inv, bv.z), 0.f));
        o4.w = f2b(fmaxf(fmaf(acc[k4 + 3], inv, bv.w), 0.f));
        *(ushort4*)&As2[r * 264 + c] = o4;
    }
    if (t == 0) nbuf[r] = n;
    __syncthreads();

    // Phase 2: 16x256 @ 256x64 mini-GEMM; wave wv owns col-tile wv (cols wv*16..+15)
    {
        const int gc = wv * 16 + t;
        floatx4 c2 = {0.f, 0.f, 0.f, 0.f};
#pragma unroll
        for (int kk = 0; kk < 8; ++kk) {
            const bf16x8 af = *(const bf16x8*)&As2[t * 264 + kk * 32 + grp * 8];
            const bf16x8 bf = *(const bf16x8*)&Bt2[(size_t)gc * 256 + kk * 32 + grp * 8];
            c2 = __builtin_amdgcn_mfma_f32_16x16x32_bf16(af, bf, c2, 0, 0, 0);
        }
        const float a_s = as2[gc];
        const float a_d = ad2[gc];
        float srg[4], drg[4];
#pragma unroll
        for (int rg = 0; rg < 4; ++rg) {
            srg[rg] = c2[rg] * a_s;
            drg[rg] = c2[rg] * a_d;
            const int row = grp * 4 + rg;
            outW[(size_t)nbuf[row] * 64 + gc] = f2b(c2[rg]);
        }
#pragma unroll
        for (int rg = 0; rg < 4; ++rg) {
            for (int o = 1; o < 16; o <<= 1) {
                srg[rg] += __shfl_xor(srg[rg], o);
                drg[rg] += __shfl_xor(drg[rg], o);
            }
        }
        if (t == 0) {
#pragma unroll
            for (int rg = 0; rg < 4; ++rg) {
                sds[wv][grp * 4 + rg] = srg[rg];
                sdd[wv][grp * 4 + rg] = drg[rg];
            }
        }
    }
    __syncthreads();
    if (threadIdx.x < 16) {
        const int rr = threadIdx.x;
        es2o[nbuf[rr]] = sds[0][rr] + sds[1][rr] + sds[2][rr] + sds[3][rr];
        ed2o[nbuf[rr]] = sdd[0][rr] + sdd[1][rr] + sdd[2][rr] + sdd[3][rr];
    }
}

// ---------------- GAT layers 2-3 FUSED with next-layer 64x64 GEMM ----------------
// 128-thread blocks (2 waves, 16 nodes; grid 3125 exact) -> 16 barrier groups/CU
// AND full 16-row A-frags (round-7 win). Phase 1: proven gatL body (8-lane
// group/node). h row -> global fp32 + bf16 -> LDS. Phase 2: 16x64 @ 64x64 MFMA;
// wave wv owns col-tiles wv*2, wv*2+1.
template <bool RES>
__global__ __launch_bounds__(128) void k_gatLG(
    const unsigned short* __restrict__ xW, const float* __restrict__ es, const float* __restrict__ ed,
    const int* __restrict__ offs, const int* __restrict__ deg, const int* __restrict__ csr,
    const int* __restrict__ perm, const float* __restrict__ bias, const float* __restrict__ gam,
    const float* __restrict__ bet, float* __restrict__ hglob,
    const unsigned short* __restrict__ Btn, const float* __restrict__ asn,
    const float* __restrict__ adn, unsigned short* __restrict__ outW,
    float* __restrict__ esn, float* __restrict__ edn_o) {
    __shared__ float ps[2][64];
    __shared__ int sbuf[2][64];
    __shared__ unsigned short As2[16 * 72];  // h bf16 rows (16 nodes), stride 72
    __shared__ int nbuf[16];
    __shared__ float sds[2][16], sdd[2][16];
    const int wv = threadIdx.x >> 6;
    const int lane = threadIdx.x & 63;
    const int g8 = lane >> 3, t8 = lane & 7;
    const int row1 = wv * 8 + g8;               // block-local row 0..15
    const int pidx = blockIdx.x * 16 + row1;    // 3125*16 = 50000 exact
    const int n = perm[pidx];
    const int off = offs[n];
    const int dg = deg[n];
    const float edn = ed[n];
    const int cb = t8 * 8;

    float acc[8];
#pragma unroll
    for (int k = 0; k < 8; ++k) acc[k] = 0.f;
    float dsum = 0.f;

    for (int base = 0; base < dg; base += 8) {
        const int idx = base + t8;
        int s_l = 0;
        float p_l = 0.f;
        if (idx < dg) {
            s_l = csr[off + idx];
            p_l = __expf(lrelu(es[s_l] + edn));
        }
        ps[wv][g8 * 8 + t8] = p_l;
        sbuf[wv][g8 * 8 + t8] = s_l;
        float pp[8];
        int ss[8];
#pragma unroll
        for (int q = 0; q < 8; ++q) {
            pp[q] = ps[wv][g8 * 8 + q];
            ss[q] = sbuf[wv][g8 * 8 + q];
        }
        uint4 u[8];
#pragma unroll
        for (int q = 0; q < 8; ++q) u[q] = *(const uint4*)&xW[(size_t)ss[q] * 64 + cb];
#pragma unroll
        for (int q = 0; q < 8; ++q) {
            dsum += pp[q];
            acc[0] = fmaf(pp[q], blo(u[q].x), acc[0]);
            acc[1] = fmaf(pp[q], bhi(u[q].x), acc[1]);
            acc[2] = fmaf(pp[q], blo(u[q].y), acc[2]);
            acc[3] = fmaf(pp[q], bhi(u[q].y), acc[3]);
            acc[4] = fmaf(pp[q], blo(u[q].z), acc[4]);
            acc[5] = fmaf(pp[q], bhi(u[q].z), acc[5]);
            acc[6] = fmaf(pp[q], blo(u[q].w), acc[6]);
            acc[7] = fmaf(pp[q], bhi(u[q].w), acc[7]);
        }
    }
    const float inv = 1.0f / fmaxf(dsum, 1e-16f);
    float hn[8];
#pragma unroll
    for (int k = 0; k < 8; ++k) {
        const int c = cb + k;
        const float y = fmaf(acc[k], inv, bias[c]);
        const float z = fmaxf(fmaf(gam[c] * y, BN_RSQ, bet[c]), 0.f);
        hn[k] = RES ? hglob[(size_t)n * 64 + c] + z : z;
    }
    *(float4*)&hglob[(size_t)n * 64 + cb] = make_float4(hn[0], hn[1], hn[2], hn[3]);
    *(float4*)&hglob[(size_t)n * 64 + cb + 4] = make_float4(hn[4], hn[5], hn[6], hn[7]);
    ushort4 u0, u1;
    u0.x = f2b(hn[0]); u0.y = f2b(hn[1]); u0.z = f2b(hn[2]); u0.w = f2b(hn[3]);
    u1.x = f2b(hn[4]); u1.y = f2b(hn[5]); u1.z = f2b(hn[6]); u1.w = f2b(hn[7]);
    *(ushort4*)&As2[row1 * 72 + cb] = u0;
    *(ushort4*)&As2[row1 * 72 + cb + 4] = u1;
    if (t8 == 0) nbuf[row1] = n;
    __syncthreads();

    // Phase 2: 16x64 @ 64x64; wave wv owns col-tiles wv*2, wv*2+1
    {
        const int quad = lane >> 4, l16 = lane & 15;
        float sacc[4] = {0.f, 0.f, 0.f, 0.f};
        float dacc[4] = {0.f, 0.f, 0.f, 0.f};
#pragma unroll
        for (int ci = 0; ci < 2; ++ci) {
            const int ct = wv * 2 + ci;
            const int gc = ct * 16 + l16;
            floatx4 c2 = {0.f, 0.f, 0.f, 0.f};
#pragma unroll
            for (int kk = 0; kk < 2; ++kk) {
                const bf16x8 af = *(const bf16x8*)&As2[l16 * 72 + kk * 32 + quad * 8];
                const bf16x8 bf = *(const bf16x8*)&Btn[(size_t)gc * 64 + kk * 32 + quad * 8];
                c2 = __builtin_amdgcn_mfma_f32_16x16x32_bf16(af, bf, c2, 0, 0, 0);
            }
            const float a_s = asn[gc];
            const float a_d = adn[gc];
#pragma unroll
            for (int rg = 0; rg < 4; ++rg) {
                sacc[rg] = fmaf(c2[rg], a_s, sacc[rg]);
                dacc[rg] = fmaf(c2[rg], a_d, dacc[rg]);
                const int row = quad * 4 + rg;
                outW[(size_t)nbuf[row] * 64 + gc] = f2b(c2[rg]);
            }
        }
#pragma unroll
        for (int rg = 0; rg < 4; ++rg) {
            for (int o = 1; o < 16; o <<= 1) {
                sacc[rg] += __shfl_xor(sacc[rg], o);
                dacc[rg] += __shfl_xor(dacc[rg], o);
            }
        }
        if (l16 == 0) {
#pragma unroll
            for (int rg = 0; rg < 4; ++rg) {
                sds[wv][quad * 4 + rg] = sacc[rg];
                sdd[wv][quad * 4 + rg] = dacc[rg];
            }
        }
    }
    __syncthreads();
    if (threadIdx.x < 16) {
        const int rr = threadIdx.x;
        esn[nbuf[rr]] = sds[0][rr] + sds[1][rr];
        edn_o[nbuf[rr]] = sdd[0][rr] + sdd[1][rr];
    }
}

// ---------------- final GAT layer (residual, no next GEMM, no bf16 out) ----------------
__global__ __launch_bounds__(256) void k_gatF(
    const unsigned short* __restrict__ xW, const float* __restrict__ es, const float* __restrict__ ed,
    const int* __restrict__ offs, const int* __restrict__ deg, const int* __restrict__ csr,
    const int* __restrict__ perm, const float* __restrict__ bias, const float* __restrict__ gam,
    const float* __restrict__ bet, float* __restrict__ h) {
    __shared__ float ps[4][64];
    __shared__ int sbuf[4][64];
    const int wv = threadIdx.x >> 6;
    const int lane = threadIdx.x & 63;
    const int grp = lane >> 3, t = lane & 7;
    const int pidx = blockIdx.x * 32 + wv * 8 + grp;
    if (pidx >= N_NODES) return;
    const int n = perm[pidx];
    const int off = offs[n];
    const int dg = deg[n];
    const float edn = ed[n];
    const int cb = t * 8;

    float acc[8];
#pragma unroll
    for (int k = 0; k < 8; ++k) acc[k] = 0.f;
    float dsum = 0.f;

    for (int base = 0; base < dg; base += 8) {
        const int idx = base + t;
        int s_l = 0;
        float p_l = 0.f;
        if (idx < dg) {
            s_l = csr[off + idx];
            p_l = __expf(lrelu(es[s_l] + edn));
        }
        ps[wv][grp * 8 + t] = p_l;
        sbuf[wv][grp * 8 + t] = s_l;
        float pp[8];
        int ss[8];
#pragma unroll
        for (int q = 0; q < 8; ++q) {
            pp[q] = ps[wv][grp * 8 + q];
            ss[q] = sbuf[wv][grp * 8 + q];
        }
        uint4 u[8];
#pragma unroll
        for (int q = 0; q < 8; ++q) u[q] = *(const uint4*)&xW[(size_t)ss[q] * 64 + cb];
#pragma unroll
        for (int q = 0; q < 8; ++q) {
            dsum += pp[q];
            acc[0] = fmaf(pp[q], blo(u[q].x), acc[0]);
            acc[1] = fmaf(pp[q], bhi(u[q].x), acc[1]);
            acc[2] = fmaf(pp[q], blo(u[q].y), acc[2]);
            acc[3] = fmaf(pp[q], bhi(u[q].y), acc[3]);
            acc[4] = fmaf(pp[q], blo(u[q].z), acc[4]);
            acc[5] = fmaf(pp[q], bhi(u[q].z), acc[5]);
            acc[6] = fmaf(pp[q], blo(u[q].w), acc[6]);
            acc[7] = fmaf(pp[q], bhi(u[q].w), acc[7]);
        }
    }
    const float inv = 1.0f / fmaxf(dsum, 1e-16f);
    float hn[8];
#pragma unroll
    for (int k = 0; k < 8; ++k) {
        const int c = cb + k;
        const float y = fmaf(acc[k], inv, bias[c]);
        const float z = fmaxf(fmaf(gam[c] * y, BN_RSQ, bet[c]), 0.f);
        hn[k] = h[(size_t)n * 64 + c] + z;
    }
    *(float4*)&h[(size_t)n * 64 + cb] = make_float4(hn[0], hn[1], hn[2], hn[3]);
    *(float4*)&h[(size_t)n * 64 + cb + 4] = make_float4(hn[4], hn[5], hn[6], hn[7]);
}

// ---------------- mean pool: one block per graph ----------------
__global__ __launch_bounds__(256) void k_pool2(const float* __restrict__ h,
                                               const int* __restrict__ bounds,
                                               float* __restrict__ hp) {
    __shared__ float part[4][64];
    const int g = blockIdx.x;
    const int lane = threadIdx.x & 63;
    const int wid = threadIdx.x >> 6;
    const int s = bounds[g], e = bounds[g + 1];
    float acc = 0.f;
    for (int n = s + wid; n < e; n += 4) acc += h[n * 64 + lane];
    part[wid][lane] = acc;
    __syncthreads();
    if (wid == 0) {
        float v = part[0][lane] + part[1][lane] + part[2][lane] + part[3][lane];
        hp[g * 64 + lane] = v / fmaxf((float)(e - s), 1.0f);
    }
}

// ---------------- MLP head, single block ----------------
__global__ __launch_bounds__(256) void k_head(const float* __restrict__ hpg,
                                              const float* __restrict__ Wh1,
                                              const float* __restrict__ bh1,
                                              const float* __restrict__ Wh2,
                                              const float* __restrict__ bh2,
                                              float* __restrict__ out) {
    __shared__ float hp[64 * 64];
    __shared__ float t1[64 * 128];
    const int tid = threadIdx.x;
    for (int i = tid; i < 64 * 64; i += 256) hp[i] = hpg[i];
    __syncthreads();
    for (int i = tid; i < 64 * 128; i += 256) {
        int g = i >> 7, j = i & 127;
        float s = bh1[j];
        for (int k = 0; k < 64; ++k) s = fmaf(hp[g * 64 + k], Wh1[k * 128 + j], s);
        t1[i] = fmaxf(s, 0.f);
    }
    __syncthreads();
    for (int i = tid; i < 640; i += 256) {
        int g = i / 10, j = i - g * 10;
        float s = bh2[j];
        for (int k = 0; k < 128; ++k) s = fmaf(t1[g * 128 + k], Wh2[k * 10 + j], s);
        out[i] = s;
    }
}

extern "C" void kernel_launch(void* const* d_in, const int* in_sizes, int n_in,
                              void* d_out, int out_size, void* d_ws, size_t ws_size,
                              hipStream_t stream) {
    const float* x = (const float*)d_in[1];
    const int* ei = (const int*)d_in[2];
    const int* batch = (const int*)d_in[3];
    const float* W1 = (const float*)d_in[4];
    const float* a_src1 = (const float*)d_in[5];
    const float* a_dst1 = (const float*)d_in[6];
    const float* b1 = (const float*)d_in[7];
    const float* W2 = (const float*)d_in[8];
    const float* a_src2 = (const float*)d_in[9];
    const float* a_dst2 = (const float*)d_in[10];
    const float* b2 = (const float*)d_in[11];
    const float* g2 = (const float*)d_in[12];
    const float* be2 = (const float*)d_in[13];
    const float* W3 = (const float*)d_in[14];
    const float* a_src3 = (const float*)d_in[15];
    const float* a_dst3 = (const float*)d_in[16];
    const float* b3 = (const float*)d_in[17];
    const float* g3 = (const float*)d_in[18];
    const float* be3 = (const float*)d_in[19];
    const float* W4 = (const float*)d_in[20];
    const float* a_src4 = (const float*)d_in[21];
    const float* a_dst4 = (const float*)d_in[22];
    const float* b4 = (const float*)d_in[23];
    const float* g4 = (const float*)d_in[24];
    const float* be4 = (const float*)d_in[25];
    const float* Wh1 = (const float*)d_in[26];
    const float* bh1 = (const float*)d_in[27];
    const float* Wh2 = (const float*)d_in[28];
    const float* bh2 = (const float*)d_in[29];
    float* out = (float*)d_out;

    // workspace layout
    char* p = (char*)d_ws;
    auto alloc = [&](size_t bytes) {
        void* r = (void*)p;
        p += (bytes + 255) & ~(size_t)255;
        return r;
    };
    unsigned short* bufA1 = (unsigned short*)alloc((size_t)N_NODES * 256 * 2);  // xW1 bf16
    unsigned short* bufB = (unsigned short*)alloc((size_t)N_NODES * 64 * 2);    // xW2 bf16
    unsigned short* bufC = (unsigned short*)alloc((size_t)N_NODES * 64 * 2);    // xW3 bf16
    unsigned short* bufD = (unsigned short*)alloc((size_t)N_NODES * 64 * 2);    // xW4 bf16
    float* h = (float*)alloc((size_t)N_NODES * 64 * 4);                         // h fp32
    float* es1 = (float*)alloc((size_t)N_NODES * 4 * 4);
    float* ed1 = (float*)alloc((size_t)N_NODES * 4 * 4);
    float* es2 = (float*)alloc((size_t)N_NODES * 4);
    float* ed2 = (float*)alloc((size_t)N_NODES * 4);
    float* es3 = (float*)alloc((size_t)N_NODES * 4);
    float* ed3 = (float*)alloc((size_t)N_NODES * 4);
    float* es4 = (float*)alloc((size_t)N_NODES * 4);
    float* ed4 = (float*)alloc((size_t)N_NODES * 4);
    int* offs = (int*)alloc((size_t)N_NODES * 4);
    int* csr = (int*)alloc((size_t)N_EDGES * 4);
    int* perm = (int*)alloc((size_t)N_NODES * 4);
    int* bounds = (int*)alloc((size_t)(N_GRAPHS + 1) * 4);
    int* bh_hist = (int*)alloc((size_t)NB_SCAN * 64 * 4);
    int* bb = (int*)alloc((size_t)NB_SCAN * 64 * 4);
    float* hpool = (float*)alloc((size_t)N_GRAPHS * 64 * 4);
    unsigned short* Wt1 = (unsigned short*)alloc((size_t)128 * 256 * 2);
    unsigned short* Wt2 = (unsigned short*)alloc((size_t)256 * 64 * 2);
    unsigned short* Wt3 = (unsigned short*)alloc((size_t)64 * 64 * 2);
    unsigned short* Wt4 = (unsigned short*)alloc((size_t)64 * 64 * 2);
    char* z0 = p;  // everything below gets zeroed each call
    int* deg = (int*)alloc((size_t)N_NODES * 4);
    int* cur = (int*)alloc((size_t)N_NODES * 4);
    int* total = (int*)alloc(256);
    size_t zbytes = (size_t)(p - z0);
    hipMemsetAsync(z0, 0, zbytes, stream);

    const int edgeBlocks = (N_EDGES + 255) / 256;
    const int mgemmBlocks = (N_NODES + 63) / 64;
    const int gat1Blocks = (N_NODES + 15) / 16;  // 3125 exact, 256-thread blocks
    const int gatLGBlocks = N_NODES / 16;        // 3125 exact, 128-thread blocks
    const int gatFBlocks = (N_NODES + 31) / 32;

    // fused prep: degree count + weight bf16 transposes
    k_prep<<<edgeBlocks, 256, 0, stream>>>(ei, deg, W1, W2, W3, W4, Wt1, Wt2, Wt3, Wt4);

    // CSR offsets + LPT histogram + graph bounds; bucket scan; merged fill+perm
    k_offs<<<NB_SCAN, 256, 0, stream>>>(deg, offs, total, batch, bounds, bh_hist);
    k_pscan<<<1, 256, 0, stream>>>(bh_hist, bb);
    k_fillperm<<<edgeBlocks, 256, 0, stream>>>(ei, offs, cur, csr, deg, bb, perm);

    // layer 1 GEMM: xW1 + attention dots
    k_mgemm<128, 256, 4, true><<<mgemmBlocks, 256, 0, stream>>>(x, Wt1, a_src1, a_dst1,
                                                                bufA1, es1, ed1, N_NODES);
    // layer 1 gather + FUSED layer-2 projection GEMM (x1 never hits HBM)
    k_gat1f<<<gat1Blocks, 256, 0, stream>>>(bufA1, es1, ed1, offs, deg, csr, perm, b1,
                                            Wt2, a_src2, a_dst2, bufB, es2, ed2);

    // layer 2 gather + BN + relu + FUSED layer-3 GEMM
    k_gatLG<false><<<gatLGBlocks, 128, 0, stream>>>(bufB, es2, ed2, offs, deg, csr, perm,
                                                    b2, g2, be2, h, Wt3, a_src3, a_dst3,
                                                    bufC, es3, ed3);
    // layer 3 residual gather + FUSED layer-4 GEMM
    k_gatLG<true><<<gatLGBlocks, 128, 0, stream>>>(bufC, es3, ed3, offs, deg, csr, perm,
                                                   b3, g3, be3, h, Wt4, a_src4, a_dst4,
                                                   bufD, es4, ed4);
    // layer 4 residual gather (final)
    k_gatF<<<gatFBlocks, 256, 0, stream>>>(bufD, es4, ed4, offs, deg, csr, perm, b4, g4, be4, h);

    // pool + head (batch sorted -> contiguous ranges, no atomics)
    k_pool2<<<N_GRAPHS, 256, 0, stream>>>(h, bounds, hpool);
    k_head<<<1, 256, 0, stream>>>(hpool, Wh1, bh1, Wh2, bh2, out);
}